// Round 6
// baseline (352.355 us; speedup 1.0000x reference)
//
#include <hip/hip_runtime.h>

#define N_NODES 50000
#define N_EDGES 600000
#define HID 128
#define N_GRAPHS 512
#define BN_EPS 1e-5f
#define INV_N (1.0f / 50000.0f)
#define SLICE_STRIDE 800000     // 50000 * 16 u16 elems per column-slice
#define NSLICES 8
#define GATHER_GROUPS 391       // ceil(50000/128)
#define IDXCAP 4096

typedef __attribute__((ext_vector_type(8))) short bf16x8;
typedef __attribute__((ext_vector_type(4))) float f32x4;

__device__ __forceinline__ unsigned short f2b(float f) {
    unsigned u = __float_as_uint(f);
    return (unsigned short)((u + 0x7FFFu + ((u >> 16) & 1u)) >> 16);
}
__device__ __forceinline__ float b2f(unsigned short h) {
    return __uint_as_float(((unsigned)h) << 16);
}

// sum the 8 stats replicas
__device__ __forceinline__ float stats_sum(const float* __restrict__ s, int idx) {
    float v = 0.f;
#pragma unroll
    for (int r = 0; r < 8; r++) v += s[r * 256 + idx];
    return v;
}

// ---------------------------------------------------------------------------
// prep: x -> bf16 (16-col sliced) | transpose+convert 6 weight mats | degree
// ---------------------------------------------------------------------------
#define CONVX_BLOCKS 6250
#define WCONV_BLOCKS 384
#define DEG_BLOCKS   2344
__global__ __launch_bounds__(256) void prep_kernel(
    const float* __restrict__ x, const float* __restrict__ gw1, const float* __restrict__ gw2,
    const float* __restrict__ swl, const float* __restrict__ swr, const int* __restrict__ dst,
    unsigned short* __restrict__ x16, unsigned short* __restrict__ wt, int* __restrict__ deg)
{
    int b = blockIdx.x;
    int t = threadIdx.x;
    if (b < CONVX_BLOCKS) {
        int gid = b * 256 + t;
        int i = gid >> 5, l = gid & 31;
        if (i >= N_NODES) return;
        int c0 = l * 4;
        float4 v = *(const float4*)(x + (size_t)i * 128 + c0);
        ushort4 o;
        o.x = f2b(v.x); o.y = f2b(v.y); o.z = f2b(v.z); o.w = f2b(v.w);
        // sliced: slice = c0>>4 = l>>2 ; off = c0&15 = (l&3)*4
        *(ushort4*)(x16 + (size_t)(l >> 2) * SLICE_STRIDE + (size_t)i * 16 + (l & 3) * 4) = o;
    } else if (b < CONVX_BLOCKS + WCONV_BLOCKS) {
        int gid = (b - CONVX_BLOCKS) * 256 + t;   // < 6*16384
        int m = gid >> 14;
        int e = gid & 16383;
        int k = e >> 7;
        int n = e & 127;
        const float* src = (m == 0) ? gw1 : (m == 1) ? gw2 : (m == 2) ? swl
                         : (m == 3) ? swr : (m == 4) ? (swl + 16384) : (swr + 16384);
        wt[m * 16384 + n * 128 + k] = f2b(src[k * 128 + n]);
    } else {
        int e = (b - CONVX_BLOCKS - WCONV_BLOCKS) * 256 + t;
        if (e < N_EDGES) atomicAdd(&deg[dst[e]], 1);
    }
}

// ---------------------------------------------------------------------------
// alloc (per-block scan + atomic base) + gstart (binary search), fused
// ---------------------------------------------------------------------------
#define ALLOC_BLOCKS 196
__global__ __launch_bounds__(256) void alloc_kernel(int* __restrict__ cursor,
                                                    int* __restrict__ row_beg,
                                                    float* __restrict__ inv_deg,
                                                    int* __restrict__ total,
                                                    const int* __restrict__ batch,
                                                    int* __restrict__ gstart) {
    if (blockIdx.x >= ALLOC_BLOCKS) {
        int g = (blockIdx.x - ALLOC_BLOCKS) * 256 + threadIdx.x;
        if (g > N_GRAPHS) return;
        int lo = 0, hi = N_NODES;
        while (lo < hi) {
            int mid = (lo + hi) >> 1;
            if (batch[mid] < g) lo = mid + 1; else hi = mid;
        }
        gstart[g] = lo;
        return;
    }
    __shared__ int tmp[256];
    __shared__ int base;
    int i = blockIdx.x * 256 + threadIdx.x;
    int d = (i < N_NODES) ? cursor[i] : 0;
    tmp[threadIdx.x] = d;
    __syncthreads();
#pragma unroll
    for (int off = 1; off < 256; off <<= 1) {
        int v = (threadIdx.x >= off) ? tmp[threadIdx.x - off] : 0;
        __syncthreads();
        tmp[threadIdx.x] += v;
        __syncthreads();
    }
    if (threadIdx.x == 255) base = atomicAdd(total, tmp[255]);
    __syncthreads();
    if (i < N_NODES) {
        int b = base + tmp[threadIdx.x] - d;
        row_beg[i] = b;
        cursor[i] = b;
        inv_deg[i] = 1.0f / fmaxf((float)d, 1.0f);
    }
}

__global__ void csr_fill_kernel(const int* __restrict__ src, const int* __restrict__ dst,
                                int* __restrict__ cursor, unsigned short* __restrict__ csr_src, int nE) {
    int e = blockIdx.x * blockDim.x + threadIdx.x;
    if (e < nE) {
        int pos = atomicAdd(&cursor[dst[e]], 1);
        csr_src[pos] = (unsigned short)src[e];
    }
}

// ---------------------------------------------------------------------------
// XCD-sliced gather: block = (group of 128 nodes, slice of 16 cols).
// slice = blockIdx & 7 -> round-robin pins each slice to one XCD; its L2
// holds the 1.6 MB slice + 1.6 MB agg writes (3.2 MB < 4 MB). 2 lanes/node,
// 16B loads, 8-deep unroll.
// AFF: neighbors pass through relu(v*c+s) (BN affine from stats_in, computed
//      into LDS for the slice's 16 cols), agg scaled by inv_deg (mean).
// ---------------------------------------------------------------------------
template<bool AFF>
__global__ __launch_bounds__(256, 6) void gather_slice_kernel(
    const unsigned short* __restrict__ feat_s,
    const int* __restrict__ row_beg, const int* __restrict__ row_end,
    const unsigned short* __restrict__ csr_src,
    const float* __restrict__ inv_deg,
    const float* __restrict__ stats_in, const float* __restrict__ gamma,
    const float* __restrict__ beta,
    unsigned short* __restrict__ agg_s)
{
    __shared__ unsigned short idxbuf[IDXCAP];
    __shared__ float csc[16], css[16];
    const int t = threadIdx.x;
    const int slice = blockIdx.x & 7;
    const int grp = blockIdx.x >> 3;
    const int node0 = grp * 128;
    const int nlast = (node0 + 127 < N_NODES) ? node0 + 127 : N_NODES - 1;
    const int node = node0 + (t >> 1);
    const int l8 = (t & 1) * 8;
    const unsigned short* fbase = feat_s + (size_t)slice * SLICE_STRIDE + l8;

    if (AFF && t < 16) {
        int col = slice * 16 + t;
        float mu = stats_sum(stats_in, col) * INV_N;
        float var = stats_sum(stats_in, 128 + col) * INV_N - mu * mu;
        float rs = rsqrtf(var + BN_EPS);
        float c = gamma[col] * rs;
        csc[t] = c;
        css[t] = beta[col] - mu * c;
    }

    const int ebeg = row_beg[node0];
    const int ecnt = row_end[nlast] - ebeg;
    const bool lds_ok = (ecnt <= IDXCAP);
    if (lds_ok)
        for (int i = t; i < ecnt; i += 256) idxbuf[i] = csr_src[ebeg + i];
    __syncthreads();
    if (node >= N_NODES) return;

    float cc[8], ss[8];
    if (AFF) {
#pragma unroll
        for (int j = 0; j < 8; j++) { cc[j] = csc[l8 + j]; ss[j] = css[l8 + j]; }
    }

    const int beg = row_beg[node];
    const int deg = row_end[node] - beg;

    float a[8];
#pragma unroll
    for (int j = 0; j < 8; j++) a[j] = 0.f;

    if (lds_ok) {
        const int off = beg - ebeg;
        int e = 0;
        for (; e + 7 < deg; e += 8) {
            int s[8];
#pragma unroll
            for (int u = 0; u < 8; u++) s[u] = idxbuf[off + e + u];
            bf16x8 v[8];
#pragma unroll
            for (int u = 0; u < 8; u++)
                v[u] = *(const bf16x8*)(fbase + (size_t)s[u] * 16);
#pragma unroll
            for (int u = 0; u < 8; u++)
#pragma unroll
                for (int j = 0; j < 8; j++) {
                    float tv = b2f((unsigned short)v[u][j]);
                    if (AFF) tv = fmaxf(tv * cc[j] + ss[j], 0.f);
                    a[j] += tv;
                }
        }
        for (; e + 3 < deg; e += 4) {
            int s[4];
#pragma unroll
            for (int u = 0; u < 4; u++) s[u] = idxbuf[off + e + u];
            bf16x8 v[4];
#pragma unroll
            for (int u = 0; u < 4; u++)
                v[u] = *(const bf16x8*)(fbase + (size_t)s[u] * 16);
#pragma unroll
            for (int u = 0; u < 4; u++)
#pragma unroll
                for (int j = 0; j < 8; j++) {
                    float tv = b2f((unsigned short)v[u][j]);
                    if (AFF) tv = fmaxf(tv * cc[j] + ss[j], 0.f);
                    a[j] += tv;
                }
        }
        for (; e < deg; e++) {
            int s0 = idxbuf[off + e];
            bf16x8 v0 = *(const bf16x8*)(fbase + (size_t)s0 * 16);
#pragma unroll
            for (int j = 0; j < 8; j++) {
                float tv = b2f((unsigned short)v0[j]);
                if (AFF) tv = fmaxf(tv * cc[j] + ss[j], 0.f);
                a[j] += tv;
            }
        }
    } else {
        // pathological skew fallback
        for (int e = beg; e < beg + deg; e++) {
            int s0 = csr_src[e];
            bf16x8 v0 = *(const bf16x8*)(fbase + (size_t)s0 * 16);
#pragma unroll
            for (int j = 0; j < 8; j++) {
                float tv = b2f((unsigned short)v0[j]);
                if (AFF) tv = fmaxf(tv * cc[j] + ss[j], 0.f);
                a[j] += tv;
            }
        }
    }

    if (AFF) {
        float sc = inv_deg[node];
#pragma unroll
        for (int j = 0; j < 8; j++) a[j] *= sc;
    }
    bf16x8 o;
#pragma unroll
    for (int j = 0; j < 8; j++) o[j] = (short)f2b(a[j]);
    *(bf16x8*)(agg_s + (size_t)slice * SLICE_STRIDE + (size_t)node * 16 + l8) = o;
}

// ---------------------------------------------------------------------------
// Fused GIN GEMM (sliced A/C): Cb = bf16( relu((X+AGG)@W1+b1) @ W2 + b2 ).
// Weights register-stationary; T1 via 32x136 LDS tile. Stats 8-replica.
// ---------------------------------------------------------------------------
__global__ __launch_bounds__(256, 2) void gemm_gin_kernel(
    const unsigned short* __restrict__ X, const unsigned short* __restrict__ AGG,
    const unsigned short* __restrict__ W1t, const unsigned short* __restrict__ W2t,
    const float* __restrict__ b1, const float* __restrict__ b2,
    float* __restrict__ stats, unsigned short* __restrict__ Cb,
    int M, int ntiles)
{
    __shared__ unsigned short t1[32][136];
    __shared__ float red[2][128];

    const int t = threadIdx.x;
    const int wave = t >> 6;
    const int lane = t & 63;
    const int colhalf = wave & 1;
    const int rowpair = wave >> 1;
    const int m16 = lane & 15;
    const int quad = lane >> 4;
    const int k0 = quad * 8;
    const int colbase = colhalf * 64;
    const int lrow = rowpair * 16 + m16;

    const bf16x8 zero8 = {0, 0, 0, 0, 0, 0, 0, 0};

    bf16x8 w1f[4][4], w2f[4][4];
#pragma unroll
    for (int ct = 0; ct < 4; ct++) {
        int col = colbase + ct * 16 + m16;
#pragma unroll
        for (int kc = 0; kc < 4; kc++) {
            w1f[ct][kc] = *(const bf16x8*)(W1t + (size_t)col * 128 + kc * 32 + k0);
            w2f[ct][kc] = *(const bf16x8*)(W2t + (size_t)col * 128 + kc * 32 + k0);
        }
    }
    f32x4 bs1[4], bs2[4];
#pragma unroll
    for (int ct = 0; ct < 4; ct++) {
        bs1[ct] = *(const f32x4*)(b1 + colbase + ct * 16 + quad * 4);
        bs2[ct] = *(const f32x4*)(b2 + colbase + ct * 16 + quad * 4);
    }

    float psum[4][4], psq[4][4];
#pragma unroll
    for (int ct = 0; ct < 4; ct++)
#pragma unroll
        for (int r = 0; r < 4; r++) { psum[ct][r] = 0.f; psq[ct][r] = 0.f; }

    for (int tile = blockIdx.x; tile < ntiles; tile += gridDim.x) {
        int arow = tile * 32 + rowpair * 16 + m16;
        bool aok = arow < M;

        // A = bf16(x + agg); col = kc*32 + quad*8 -> slice = 2*kc + (quad>>1)
        bf16x8 a[4];
#pragma unroll
        for (int kc = 0; kc < 4; kc++) {
            if (aok) {
                size_t aoff = (size_t)(kc * 2 + (quad >> 1)) * SLICE_STRIDE
                            + (size_t)arow * 16 + (quad & 1) * 8;
                bf16x8 vx = *(const bf16x8*)(X + aoff);
                bf16x8 vg = *(const bf16x8*)(AGG + aoff);
                bf16x8 r;
#pragma unroll
                for (int i = 0; i < 8; i++)
                    r[i] = (short)f2b(b2f((unsigned short)vx[i]) + b2f((unsigned short)vg[i]));
                a[kc] = r;
            } else {
                a[kc] = zero8;
            }
        }

        // phase 1
        f32x4 acc[4];
#pragma unroll
        for (int ct = 0; ct < 4; ct++) acc[ct] = (f32x4){0.f, 0.f, 0.f, 0.f};
#pragma unroll
        for (int kc = 0; kc < 4; kc++)
#pragma unroll
            for (int ct = 0; ct < 4; ct++)
                acc[ct] = __builtin_amdgcn_mfma_f32_16x16x32_bf16(w1f[ct][kc], a[kc], acc[ct], 0, 0, 0);

        __syncthreads();   // previous tile's t1 reads done
#pragma unroll
        for (int ct = 0; ct < 4; ct++) {
            f32x4 v = acc[ct] + bs1[ct];
            ushort4 o;
            o.x = f2b(fmaxf(v[0], 0.f));
            o.y = f2b(fmaxf(v[1], 0.f));
            o.z = f2b(fmaxf(v[2], 0.f));
            o.w = f2b(fmaxf(v[3], 0.f));
            *(ushort4*)&t1[lrow][colbase + ct * 16 + quad * 4] = o;
        }
        __syncthreads();

        // phase 2
        bf16x8 ta[4];
#pragma unroll
        for (int kc = 0; kc < 4; kc++)
            ta[kc] = *(const bf16x8*)&t1[lrow][kc * 32 + k0];

        f32x4 acc2[4];
#pragma unroll
        for (int ct = 0; ct < 4; ct++) acc2[ct] = (f32x4){0.f, 0.f, 0.f, 0.f};
#pragma unroll
        for (int kc = 0; kc < 4; kc++)
#pragma unroll
            for (int ct = 0; ct < 4; ct++)
                acc2[ct] = __builtin_amdgcn_mfma_f32_16x16x32_bf16(w2f[ct][kc], ta[kc], acc2[ct], 0, 0, 0);

        if (arow < M) {
#pragma unroll
            for (int ct = 0; ct < 4; ct++) {
                f32x4 v = acc2[ct] + bs2[ct];
#pragma unroll
                for (int r = 0; r < 4; r++) { psum[ct][r] += v[r]; psq[ct][r] += v[r] * v[r]; }
                ushort4 o;
                o.x = f2b(v[0]); o.y = f2b(v[1]); o.z = f2b(v[2]); o.w = f2b(v[3]);
                int cs = (colbase >> 4) + ct;
                *(ushort4*)(Cb + (size_t)cs * SLICE_STRIDE + (size_t)arow * 16 + quad * 4) = o;
            }
        }
    }

    // stats flush (8-replica)
#pragma unroll
    for (int ct = 0; ct < 4; ct++)
#pragma unroll
        for (int r = 0; r < 4; r++) {
#pragma unroll
            for (int mask = 1; mask <= 8; mask <<= 1) {
                psum[ct][r] += __shfl_xor(psum[ct][r], mask, 64);
                psq[ct][r]  += __shfl_xor(psq[ct][r], mask, 64);
            }
        }
    __syncthreads();
    if (m16 == 0) {
#pragma unroll
        for (int ct = 0; ct < 4; ct++)
#pragma unroll
            for (int r = 0; r < 4; r++)
                red[rowpair][colbase + ct * 16 + quad * 4 + r] = psum[ct][r];
    }
    __syncthreads();
    if (t < 128) atomicAdd(&stats[(blockIdx.x & 7) * 256 + t], red[0][t] + red[1][t]);
    __syncthreads();
    if (m16 == 0) {
#pragma unroll
        for (int ct = 0; ct < 4; ct++)
#pragma unroll
            for (int r = 0; r < 4; r++)
                red[rowpair][colbase + ct * 16 + quad * 4 + r] = psq[ct][r];
    }
    __syncthreads();
    if (t < 128) atomicAdd(&stats[(blockIdx.x & 7) * 256 + 128 + t], red[0][t] + red[1][t]);
}

// ---------------------------------------------------------------------------
// Dual-matrix GEMM (SAGE, sliced A/C): Cb = bf16(A1@W1 + act(Hp)@W2 + bias).
// act(v) = relu(v*c+s), affine computed from stats_in into LDS — the hact
// buffer never exists. Stats_out 8-replica.
// ---------------------------------------------------------------------------
__global__ __launch_bounds__(256) void gemm_dual_kernel(
    const unsigned short* __restrict__ A1, const unsigned short* __restrict__ Hp,
    const unsigned short* __restrict__ W1t, const unsigned short* __restrict__ W2t,
    const float* __restrict__ bias,
    const float* __restrict__ stats_in, const float* __restrict__ gamma,
    const float* __restrict__ beta,
    float* __restrict__ stats_out,
    unsigned short* __restrict__ Cb, int M, int ntiles)
{
    __shared__ float red[128];
    __shared__ float csc[128], css[128];

    const int t = threadIdx.x;
    const int wave = t >> 6;
    const int lane = t & 63;
    const int m16 = lane & 15;
    const int quad = lane >> 4;
    const int k0 = quad * 8;
    const int colbase = wave * 32;

    const bf16x8 zero8 = {0, 0, 0, 0, 0, 0, 0, 0};

    if (t < 128) {
        float mu = stats_sum(stats_in, t) * INV_N;
        float var = stats_sum(stats_in, 128 + t) * INV_N - mu * mu;
        float rs = rsqrtf(var + BN_EPS);
        float c = gamma[t] * rs;
        csc[t] = c;
        css[t] = beta[t] - mu * c;
    }
    __syncthreads();

    // per-lane affine constants for the 8 k-cols of each kc fragment
    f32x4 acA[4], acB[4], asA[4], asB[4];
#pragma unroll
    for (int kc = 0; kc < 4; kc++) {
        int col0 = kc * 32 + quad * 8;
        acA[kc] = *(const f32x4*)&csc[col0];
        acB[kc] = *(const f32x4*)&csc[col0 + 4];
        asA[kc] = *(const f32x4*)&css[col0];
        asB[kc] = *(const f32x4*)&css[col0 + 4];
    }

    bf16x8 w1f[2][4], w2f[2][4];
#pragma unroll
    for (int ct = 0; ct < 2; ct++) {
        int col = colbase + ct * 16 + m16;
#pragma unroll
        for (int kc = 0; kc < 4; kc++) {
            w1f[ct][kc] = *(const bf16x8*)(W1t + (size_t)col * 128 + kc * 32 + k0);
            w2f[ct][kc] = *(const bf16x8*)(W2t + (size_t)col * 128 + kc * 32 + k0);
        }
    }
    f32x4 bs[2];
#pragma unroll
    for (int ct = 0; ct < 2; ct++)
        bs[ct] = *(const f32x4*)(bias + colbase + ct * 16 + quad * 4);

    float psum[2][4], psq[2][4];
#pragma unroll
    for (int ct = 0; ct < 2; ct++)
#pragma unroll
        for (int r = 0; r < 4; r++) { psum[ct][r] = 0.f; psq[ct][r] = 0.f; }

    bf16x8 a1[4], a2[4], a1n[4], a2n[4];

    int tile = blockIdx.x;
    if (tile < ntiles) {
        int arow = tile * 16 + m16;
        bool aok = arow < M;
#pragma unroll
        for (int kc = 0; kc < 4; kc++) {
            size_t aoff = (size_t)(kc * 2 + (quad >> 1)) * SLICE_STRIDE
                        + (size_t)arow * 16 + (quad & 1) * 8;
            a1[kc] = aok ? *(const bf16x8*)(A1 + aoff) : zero8;
            a2[kc] = aok ? *(const bf16x8*)(Hp + aoff) : zero8;
        }
    }

    for (; tile < ntiles; tile += gridDim.x) {
        int nt = tile + gridDim.x;
        if (nt < ntiles) {
            int arow = nt * 16 + m16;
            bool aok = arow < M;
#pragma unroll
            for (int kc = 0; kc < 4; kc++) {
                size_t aoff = (size_t)(kc * 2 + (quad >> 1)) * SLICE_STRIDE
                            + (size_t)arow * 16 + (quad & 1) * 8;
                a1n[kc] = aok ? *(const bf16x8*)(A1 + aoff) : zero8;
                a2n[kc] = aok ? *(const bf16x8*)(Hp + aoff) : zero8;
            }
        }

        f32x4 acc[2];
        acc[0] = (f32x4){0.f, 0.f, 0.f, 0.f};
        acc[1] = (f32x4){0.f, 0.f, 0.f, 0.f};
#pragma unroll
        for (int kc = 0; kc < 4; kc++) {
            // hact fragment = relu(raw*c + s), computed in-register
            bf16x8 a2c;
#pragma unroll
            for (int j = 0; j < 4; j++)
                a2c[j] = (short)f2b(fmaxf(b2f((unsigned short)a2[kc][j]) * acA[kc][j] + asA[kc][j], 0.f));
#pragma unroll
            for (int j = 0; j < 4; j++)
                a2c[4 + j] = (short)f2b(fmaxf(b2f((unsigned short)a2[kc][4 + j]) * acB[kc][j] + asB[kc][j], 0.f));
#pragma unroll
            for (int ct = 0; ct < 2; ct++) {
                acc[ct] = __builtin_amdgcn_mfma_f32_16x16x32_bf16(w1f[ct][kc], a1[kc], acc[ct], 0, 0, 0);
                acc[ct] = __builtin_amdgcn_mfma_f32_16x16x32_bf16(w2f[ct][kc], a2c, acc[ct], 0, 0, 0);
            }
        }

        int orow = tile * 16 + m16;
        if (orow < M) {
#pragma unroll
            for (int ct = 0; ct < 2; ct++) {
                f32x4 v = acc[ct] + bs[ct];
#pragma unroll
                for (int r = 0; r < 4; r++) { psum[ct][r] += v[r]; psq[ct][r] += v[r] * v[r]; }
                ushort4 o;
                o.x = f2b(v[0]); o.y = f2b(v[1]); o.z = f2b(v[2]); o.w = f2b(v[3]);
                int cs = wave * 2 + ct;
                *(ushort4*)(Cb + (size_t)cs * SLICE_STRIDE + (size_t)orow * 16 + quad * 4) = o;
            }
        }

        if (nt < ntiles) {
            a1[0] = a1n[0]; a1[1] = a1n[1]; a1[2] = a1n[2]; a1[3] = a1n[3];
            a2[0] = a2n[0]; a2[1] = a2n[1]; a2[2] = a2n[2]; a2[3] = a2n[3];
        }
    }

#pragma unroll
    for (int ct = 0; ct < 2; ct++)
#pragma unroll
        for (int r = 0; r < 4; r++) {
#pragma unroll
            for (int mask = 1; mask <= 8; mask <<= 1) {
                psum[ct][r] += __shfl_xor(psum[ct][r], mask, 64);
                psq[ct][r]  += __shfl_xor(psq[ct][r], mask, 64);
            }
        }
    if (m16 == 0) {
#pragma unroll
        for (int ct = 0; ct < 2; ct++)
#pragma unroll
            for (int r = 0; r < 4; r++)
                red[colbase + ct * 16 + quad * 4 + r] = psum[ct][r];
    }
    __syncthreads();
    if (t < 128) atomicAdd(&stats_out[(blockIdx.x & 7) * 256 + t], red[t]);
    __syncthreads();
    if (m16 == 0) {
#pragma unroll
        for (int ct = 0; ct < 2; ct++)
#pragma unroll
            for (int r = 0; r < 4; r++)
                red[colbase + ct * 16 + quad * 4 + r] = psq[ct][r];
    }
    __syncthreads();
    if (t < 128) atomicAdd(&stats_out[(blockIdx.x & 7) * 256 + 128 + t], red[t]);
}

// ---------------------------------------------------------------------------
// global mean pool (sliced input): BN affine from stats, relu, mean.
// 256 thr: 16 row-groups x 16 col-chunks (16B/lane).
// ---------------------------------------------------------------------------
__global__ __launch_bounds__(256) void pool_mean_kernel(const unsigned short* __restrict__ h_s,
                                                        const int* __restrict__ gstart,
                                                        const float* __restrict__ stats,
                                                        const float* __restrict__ gamma,
                                                        const float* __restrict__ beta,
                                                        float* __restrict__ out) {
    __shared__ float red[16][128];
    int g = blockIdx.x;
    int t = threadIdx.x;
    int grp = t >> 4;
    int ci = t & 15;
    int c0 = ci * 8;
    float c[8], b[8];
#pragma unroll
    for (int j = 0; j < 8; j++) {
        int col = c0 + j;
        float mu = stats_sum(stats, col) * INV_N;
        float var = stats_sum(stats, 128 + col) * INV_N - mu * mu;
        float rs = rsqrtf(var + BN_EPS);
        c[j] = gamma[col] * rs;
        b[j] = beta[col] - mu * c[j];
    }
    int beg = gstart[g];
    int end = gstart[g + 1];
    float sa[8];
#pragma unroll
    for (int j = 0; j < 8; j++) sa[j] = 0.f;
    // slice = c0>>4 = ci>>1, off = (ci&1)*8
    const unsigned short* base = h_s + (size_t)(ci >> 1) * SLICE_STRIDE + (ci & 1) * 8;
    for (int i = beg + grp; i < end; i += 16) {
        bf16x8 v = *(const bf16x8*)(base + (size_t)i * 16);
#pragma unroll
        for (int j = 0; j < 8; j++)
            sa[j] += fmaxf(b2f((unsigned short)v[j]) * c[j] + b[j], 0.f);
    }
#pragma unroll
    for (int j = 0; j < 8; j++) red[grp][c0 + j] = sa[j];
    __syncthreads();
    if (t < 128) {
        float cnt = fmaxf((float)(end - beg), 1.0f);
        float tot = 0.f;
#pragma unroll
        for (int r = 0; r < 16; r++) tot += red[r][t];
        out[(size_t)g * 128 + t] = tot / cnt;
    }
}

// ---------------------------------------------------------------------------
extern "C" void kernel_launch(void* const* d_in, const int* in_sizes, int n_in,
                              void* d_out, int out_size, void* d_ws, size_t ws_size,
                              hipStream_t stream) {
    const float* x    = (const float*)d_in[0];
    const int*   ei   = (const int*)d_in[1];
    const int*   src  = ei;
    const int*   dst  = ei + N_EDGES;
    const int*   batch = (const int*)d_in[2];
    const float* gw1  = (const float*)d_in[3];
    const float* gb1  = (const float*)d_in[4];
    const float* gw2  = (const float*)d_in[5];
    const float* gb2  = (const float*)d_in[6];
    const float* swl  = (const float*)d_in[7];
    const float* sbl  = (const float*)d_in[8];
    const float* swr  = (const float*)d_in[9];
    const float* bng  = (const float*)d_in[10];
    const float* bnb  = (const float*)d_in[11];
    float* out = (float*)d_out;

    // workspace layout (float units; bf16 buffers 16B-aligned)
    float* ws = (float*)d_ws;
    unsigned short* x16_s  = (unsigned short*)(ws + 0);         // sliced [8][50000][16]
    unsigned short* agg_s  = (unsigned short*)(ws + 3200000);
    unsigned short* h_a    = (unsigned short*)(ws + 6400000);   // ping
    unsigned short* h_b    = (unsigned short*)(ws + 9600000);   // pong
    unsigned short* wt     = (unsigned short*)(ws + 12800000);  // 6*16384 u16
    float*          inv_deg= ws + 12850000;                     // 50000
    int*            row_beg= (int*)(ws + 12900000);             // 50000
    int*            cursor = (int*)(ws + 12950000);             // 50000 | total | stats(3*8*256)
    int*            total  = cursor + 50000;
    float*          stats  = (float*)(cursor + 50001);          // 3 layers x 8 replicas x 256
    unsigned short* csr_src= (unsigned short*)(ws + 13100000);  // 600000 u16
    int*            gstart = (int*)(ws + 13700000);             // 513

    const int ggrid = 512;
    const int ntiles32 = (N_NODES + 31) / 32;                   // 1563
    const int ntiles16 = (N_NODES + 15) / 16;                   // 3125
    const int gather_grid = GATHER_GROUPS * NSLICES;            // 3128

    // ---- init: cursor + total + stats in one memset ----
    hipMemsetAsync(cursor, 0, (50001 + 3 * 8 * 256) * sizeof(int), stream);

    // ---- prep: x->bf16 sliced, weights->bf16^T, degree count ----
    prep_kernel<<<CONVX_BLOCKS + WCONV_BLOCKS + DEG_BLOCKS, 256, 0, stream>>>(
        x, gw1, gw2, swl, swr, dst, x16_s, wt, cursor);

    // ---- CSR ----
    alloc_kernel<<<ALLOC_BLOCKS + 3, 256, 0, stream>>>(cursor, row_beg, inv_deg, total, batch, gstart);
    csr_fill_kernel<<<(N_EDGES + 255) / 256, 256, 0, stream>>>(src, dst, cursor, csr_src, N_EDGES);

    // ---- GIN ----
    gather_slice_kernel<false><<<gather_grid, 256, 0, stream>>>(
        x16_s, row_beg, cursor, csr_src, nullptr, nullptr, nullptr, nullptr, agg_s);
    gemm_gin_kernel<<<ggrid, 256, 0, stream>>>(
        x16_s, agg_s, wt + 0 * 16384, wt + 1 * 16384, gb1, gb2,
        stats + 0 * 2048, h_a, N_NODES, ntiles32);

    // ---- SAGE 0: gather(affine-folded) h_a -> agg ; dual gemm -> h_b ----
    gather_slice_kernel<true><<<gather_grid, 256, 0, stream>>>(
        h_a, row_beg, cursor, csr_src, inv_deg,
        stats + 0 * 2048, bng + 0 * HID, bnb + 0 * HID, agg_s);
    gemm_dual_kernel<<<ggrid, 256, 0, stream>>>(
        agg_s, h_a, wt + 2 * 16384, wt + 3 * 16384, sbl + 0 * HID,
        stats + 0 * 2048, bng + 0 * HID, bnb + 0 * HID,
        stats + 1 * 2048, h_b, N_NODES, ntiles16);

    // ---- SAGE 1: h_b -> agg ; dual gemm -> h_a ----
    gather_slice_kernel<true><<<gather_grid, 256, 0, stream>>>(
        h_b, row_beg, cursor, csr_src, inv_deg,
        stats + 1 * 2048, bng + 1 * HID, bnb + 1 * HID, agg_s);
    gemm_dual_kernel<<<ggrid, 256, 0, stream>>>(
        agg_s, h_b, wt + 4 * 16384, wt + 5 * 16384, sbl + 1 * HID,
        stats + 1 * 2048, bng + 1 * HID, bnb + 1 * HID,
        stats + 2 * 2048, h_a, N_NODES, ntiles16);

    // ---- pool (BN2 affine folded) ----
    pool_mean_kernel<<<N_GRAPHS, 256, 0, stream>>>(
        h_a, gstart, stats + 2 * 2048, bng + 2 * HID, bnb + 2 * HID, out);
}

// Round 8
// 337.353 us; speedup vs baseline: 1.0445x; 1.0445x over previous
//
#include <hip/hip_runtime.h>

#define N_NODES 50000
#define N_EDGES 600000
#define HID 128
#define N_GRAPHS 512
#define BN_EPS 1e-5f
#define INV_N (1.0f / 50000.0f)
#define SLICE_STRIDE 800000     // 50000 * 16 u16 elems per column-slice
#define NSLICES 8
#define GATHER_GROUPS 391       // ceil(50000/128)
#define IDXCAP 4096

typedef __attribute__((ext_vector_type(8))) short bf16x8;
typedef __attribute__((ext_vector_type(4))) float f32x4;

__device__ __forceinline__ unsigned short f2b(float f) {
    unsigned u = __float_as_uint(f);
    return (unsigned short)((u + 0x7FFFu + ((u >> 16) & 1u)) >> 16);
}
__device__ __forceinline__ float b2f(unsigned short h) {
    return __uint_as_float(((unsigned)h) << 16);
}

// sum the 8 stats replicas
__device__ __forceinline__ float stats_sum(const float* __restrict__ s, int idx) {
    float v = 0.f;
#pragma unroll
    for (int r = 0; r < 8; r++) v += s[r * 256 + idx];
    return v;
}

// ---------------------------------------------------------------------------
// prep: x -> bf16 (16-col sliced) | transpose+convert 6 weight mats | degree
// ---------------------------------------------------------------------------
#define CONVX_BLOCKS 6250
#define WCONV_BLOCKS 384
#define DEG_BLOCKS   2344
__global__ __launch_bounds__(256) void prep_kernel(
    const float* __restrict__ x, const float* __restrict__ gw1, const float* __restrict__ gw2,
    const float* __restrict__ swl, const float* __restrict__ swr, const int* __restrict__ dst,
    unsigned short* __restrict__ x16, unsigned short* __restrict__ wt, int* __restrict__ deg)
{
    int b = blockIdx.x;
    int t = threadIdx.x;
    if (b < CONVX_BLOCKS) {
        int gid = b * 256 + t;
        int i = gid >> 5, l = gid & 31;
        if (i >= N_NODES) return;
        int c0 = l * 4;
        float4 v = *(const float4*)(x + (size_t)i * 128 + c0);
        ushort4 o;
        o.x = f2b(v.x); o.y = f2b(v.y); o.z = f2b(v.z); o.w = f2b(v.w);
        // sliced: slice = c0>>4 = l>>2 ; off = c0&15 = (l&3)*4
        *(ushort4*)(x16 + (size_t)(l >> 2) * SLICE_STRIDE + (size_t)i * 16 + (l & 3) * 4) = o;
    } else if (b < CONVX_BLOCKS + WCONV_BLOCKS) {
        int gid = (b - CONVX_BLOCKS) * 256 + t;   // < 6*16384
        int m = gid >> 14;
        int e = gid & 16383;
        int k = e >> 7;
        int n = e & 127;
        const float* src = (m == 0) ? gw1 : (m == 1) ? gw2 : (m == 2) ? swl
                         : (m == 3) ? swr : (m == 4) ? (swl + 16384) : (swr + 16384);
        wt[m * 16384 + n * 128 + k] = f2b(src[k * 128 + n]);
    } else {
        int e = (b - CONVX_BLOCKS - WCONV_BLOCKS) * 256 + t;
        if (e < N_EDGES) atomicAdd(&deg[dst[e]], 1);
    }
}

// ---------------------------------------------------------------------------
// alloc (per-block scan + atomic base) + gstart (binary search), fused
// ---------------------------------------------------------------------------
#define ALLOC_BLOCKS 196
__global__ __launch_bounds__(256) void alloc_kernel(int* __restrict__ cursor,
                                                    int* __restrict__ row_beg,
                                                    float* __restrict__ inv_deg,
                                                    int* __restrict__ total,
                                                    const int* __restrict__ batch,
                                                    int* __restrict__ gstart) {
    if (blockIdx.x >= ALLOC_BLOCKS) {
        int g = (blockIdx.x - ALLOC_BLOCKS) * 256 + threadIdx.x;
        if (g > N_GRAPHS) return;
        int lo = 0, hi = N_NODES;
        while (lo < hi) {
            int mid = (lo + hi) >> 1;
            if (batch[mid] < g) lo = mid + 1; else hi = mid;
        }
        gstart[g] = lo;
        return;
    }
    __shared__ int tmp[256];
    __shared__ int base;
    int i = blockIdx.x * 256 + threadIdx.x;
    int d = (i < N_NODES) ? cursor[i] : 0;
    tmp[threadIdx.x] = d;
    __syncthreads();
#pragma unroll
    for (int off = 1; off < 256; off <<= 1) {
        int v = (threadIdx.x >= off) ? tmp[threadIdx.x - off] : 0;
        __syncthreads();
        tmp[threadIdx.x] += v;
        __syncthreads();
    }
    if (threadIdx.x == 255) base = atomicAdd(total, tmp[255]);
    __syncthreads();
    if (i < N_NODES) {
        int b = base + tmp[threadIdx.x] - d;
        row_beg[i] = b;
        cursor[i] = b;
        inv_deg[i] = 1.0f / fmaxf((float)d, 1.0f);
    }
}

__global__ void csr_fill_kernel(const int* __restrict__ src, const int* __restrict__ dst,
                                int* __restrict__ cursor, unsigned short* __restrict__ csr_src, int nE) {
    int e = blockIdx.x * blockDim.x + threadIdx.x;
    if (e < nE) {
        int pos = atomicAdd(&cursor[dst[e]], 1);
        csr_src[pos] = (unsigned short)src[e];
    }
}

// ---------------------------------------------------------------------------
// XCD-sliced gather: block = (group of 128 nodes, slice of 16 cols).
// slice = blockIdx & 7 -> round-robin pins each slice to one XCD whose L2
// holds the 1.6 MB slice. agg writes and csr index reads are NON-TEMPORAL
// so the feature slice is the only L2-resident stream (1.6 MB << 4 MB).
// 2 lanes/node, 16B loads, 8-deep unroll. MEAN: scale by inv_deg.
// ---------------------------------------------------------------------------
template<bool MEAN>
__global__ __launch_bounds__(256) void gather_slice_kernel(
    const unsigned short* __restrict__ feat_s,
    const int* __restrict__ row_beg, const int* __restrict__ row_end,
    const unsigned short* __restrict__ csr_src,
    const float* __restrict__ inv_deg,
    unsigned short* __restrict__ out_s)
{
    __shared__ unsigned short idxbuf[IDXCAP];
    const int t = threadIdx.x;
    const int slice = blockIdx.x & 7;
    const int grp = blockIdx.x >> 3;
    const int node0 = grp * 128;
    const int nlast = (node0 + 127 < N_NODES) ? node0 + 127 : N_NODES - 1;
    const int node = node0 + (t >> 1);
    const int l8 = (t & 1) * 8;
    const unsigned short* fbase = feat_s + (size_t)slice * SLICE_STRIDE + l8;

    const int ebeg = row_beg[node0];
    const int ecnt = row_end[nlast] - ebeg;
    const bool lds_ok = (ecnt <= IDXCAP);
    if (lds_ok)
        for (int i = t; i < ecnt; i += 256)
            idxbuf[i] = __builtin_nontemporal_load(csr_src + ebeg + i);
    __syncthreads();
    if (node >= N_NODES) return;

    const int beg = row_beg[node];
    const int deg = row_end[node] - beg;

    float a[8];
#pragma unroll
    for (int j = 0; j < 8; j++) a[j] = 0.f;

    if (lds_ok) {
        const int off = beg - ebeg;
        int e = 0;
        for (; e + 7 < deg; e += 8) {
            int s[8];
#pragma unroll
            for (int u = 0; u < 8; u++) s[u] = idxbuf[off + e + u];
            bf16x8 v[8];
#pragma unroll
            for (int u = 0; u < 8; u++)
                v[u] = *(const bf16x8*)(fbase + (size_t)s[u] * 16);
#pragma unroll
            for (int u = 0; u < 8; u++)
#pragma unroll
                for (int j = 0; j < 8; j++)
                    a[j] += b2f((unsigned short)v[u][j]);
        }
        for (; e + 3 < deg; e += 4) {
            int s[4];
#pragma unroll
            for (int u = 0; u < 4; u++) s[u] = idxbuf[off + e + u];
            bf16x8 v[4];
#pragma unroll
            for (int u = 0; u < 4; u++)
                v[u] = *(const bf16x8*)(fbase + (size_t)s[u] * 16);
#pragma unroll
            for (int u = 0; u < 4; u++)
#pragma unroll
                for (int j = 0; j < 8; j++)
                    a[j] += b2f((unsigned short)v[u][j]);
        }
        for (; e < deg; e++) {
            int s0 = idxbuf[off + e];
            bf16x8 v0 = *(const bf16x8*)(fbase + (size_t)s0 * 16);
#pragma unroll
            for (int j = 0; j < 8; j++)
                a[j] += b2f((unsigned short)v0[j]);
        }
    } else {
        // pathological skew fallback
        for (int e = beg; e < beg + deg; e++) {
            int s0 = csr_src[e];
            bf16x8 v0 = *(const bf16x8*)(fbase + (size_t)s0 * 16);
#pragma unroll
            for (int j = 0; j < 8; j++)
                a[j] += b2f((unsigned short)v0[j]);
        }
    }

    if (MEAN) {
        float sc = inv_deg[node];
#pragma unroll
        for (int j = 0; j < 8; j++) a[j] *= sc;
    }
    bf16x8 o;
#pragma unroll
    for (int j = 0; j < 8; j++) o[j] = (short)f2b(a[j]);
    __builtin_nontemporal_store(o, (bf16x8*)(out_s + (size_t)slice * SLICE_STRIDE + (size_t)node * 16 + l8));
}

// ---------------------------------------------------------------------------
// Fused GIN GEMM (sliced A/C): Cb = bf16( relu((X+AGG)@W1+b1) @ W2 + b2 ).
// Weights register-stationary; T1 via 32x136 LDS tile. Stats 8-replica.
// ---------------------------------------------------------------------------
__global__ __launch_bounds__(256, 2) void gemm_gin_kernel(
    const unsigned short* __restrict__ X, const unsigned short* __restrict__ AGG,
    const unsigned short* __restrict__ W1t, const unsigned short* __restrict__ W2t,
    const float* __restrict__ b1, const float* __restrict__ b2,
    float* __restrict__ stats, unsigned short* __restrict__ Cb,
    int M, int ntiles)
{
    __shared__ unsigned short t1[32][136];
    __shared__ float red[2][128];

    const int t = threadIdx.x;
    const int wave = t >> 6;
    const int lane = t & 63;
    const int colhalf = wave & 1;
    const int rowpair = wave >> 1;
    const int m16 = lane & 15;
    const int quad = lane >> 4;
    const int k0 = quad * 8;
    const int colbase = colhalf * 64;
    const int lrow = rowpair * 16 + m16;

    const bf16x8 zero8 = {0, 0, 0, 0, 0, 0, 0, 0};

    bf16x8 w1f[4][4], w2f[4][4];
#pragma unroll
    for (int ct = 0; ct < 4; ct++) {
        int col = colbase + ct * 16 + m16;
#pragma unroll
        for (int kc = 0; kc < 4; kc++) {
            w1f[ct][kc] = *(const bf16x8*)(W1t + (size_t)col * 128 + kc * 32 + k0);
            w2f[ct][kc] = *(const bf16x8*)(W2t + (size_t)col * 128 + kc * 32 + k0);
        }
    }
    f32x4 bs1[4], bs2[4];
#pragma unroll
    for (int ct = 0; ct < 4; ct++) {
        bs1[ct] = *(const f32x4*)(b1 + colbase + ct * 16 + quad * 4);
        bs2[ct] = *(const f32x4*)(b2 + colbase + ct * 16 + quad * 4);
    }

    float psum[4][4], psq[4][4];
#pragma unroll
    for (int ct = 0; ct < 4; ct++)
#pragma unroll
        for (int r = 0; r < 4; r++) { psum[ct][r] = 0.f; psq[ct][r] = 0.f; }

    for (int tile = blockIdx.x; tile < ntiles; tile += gridDim.x) {
        int arow = tile * 32 + rowpair * 16 + m16;
        bool aok = arow < M;

        // A = bf16(x + agg); col = kc*32 + quad*8 -> slice = 2*kc + (quad>>1)
        bf16x8 a[4];
#pragma unroll
        for (int kc = 0; kc < 4; kc++) {
            if (aok) {
                size_t aoff = (size_t)(kc * 2 + (quad >> 1)) * SLICE_STRIDE
                            + (size_t)arow * 16 + (quad & 1) * 8;
                bf16x8 vx = *(const bf16x8*)(X + aoff);
                bf16x8 vg = *(const bf16x8*)(AGG + aoff);
                bf16x8 r;
#pragma unroll
                for (int i = 0; i < 8; i++)
                    r[i] = (short)f2b(b2f((unsigned short)vx[i]) + b2f((unsigned short)vg[i]));
                a[kc] = r;
            } else {
                a[kc] = zero8;
            }
        }

        // phase 1
        f32x4 acc[4];
#pragma unroll
        for (int ct = 0; ct < 4; ct++) acc[ct] = (f32x4){0.f, 0.f, 0.f, 0.f};
#pragma unroll
        for (int kc = 0; kc < 4; kc++)
#pragma unroll
            for (int ct = 0; ct < 4; ct++)
                acc[ct] = __builtin_amdgcn_mfma_f32_16x16x32_bf16(w1f[ct][kc], a[kc], acc[ct], 0, 0, 0);

        __syncthreads();   // previous tile's t1 reads done
#pragma unroll
        for (int ct = 0; ct < 4; ct++) {
            f32x4 v = acc[ct] + bs1[ct];
            ushort4 o;
            o.x = f2b(fmaxf(v[0], 0.f));
            o.y = f2b(fmaxf(v[1], 0.f));
            o.z = f2b(fmaxf(v[2], 0.f));
            o.w = f2b(fmaxf(v[3], 0.f));
            *(ushort4*)&t1[lrow][colbase + ct * 16 + quad * 4] = o;
        }
        __syncthreads();

        // phase 2
        bf16x8 ta[4];
#pragma unroll
        for (int kc = 0; kc < 4; kc++)
            ta[kc] = *(const bf16x8*)&t1[lrow][kc * 32 + k0];

        f32x4 acc2[4];
#pragma unroll
        for (int ct = 0; ct < 4; ct++) acc2[ct] = (f32x4){0.f, 0.f, 0.f, 0.f};
#pragma unroll
        for (int kc = 0; kc < 4; kc++)
#pragma unroll
            for (int ct = 0; ct < 4; ct++)
                acc2[ct] = __builtin_amdgcn_mfma_f32_16x16x32_bf16(w2f[ct][kc], ta[kc], acc2[ct], 0, 0, 0);

        if (arow < M) {
#pragma unroll
            for (int ct = 0; ct < 4; ct++) {
                f32x4 v = acc2[ct] + bs2[ct];
#pragma unroll
                for (int r = 0; r < 4; r++) { psum[ct][r] += v[r]; psq[ct][r] += v[r] * v[r]; }
                ushort4 o;
                o.x = f2b(v[0]); o.y = f2b(v[1]); o.z = f2b(v[2]); o.w = f2b(v[3]);
                int cs = (colbase >> 4) + ct;
                *(ushort4*)(Cb + (size_t)cs * SLICE_STRIDE + (size_t)arow * 16 + quad * 4) = o;
            }
        }
    }

    // stats flush (8-replica)
#pragma unroll
    for (int ct = 0; ct < 4; ct++)
#pragma unroll
        for (int r = 0; r < 4; r++) {
#pragma unroll
            for (int mask = 1; mask <= 8; mask <<= 1) {
                psum[ct][r] += __shfl_xor(psum[ct][r], mask, 64);
                psq[ct][r]  += __shfl_xor(psq[ct][r], mask, 64);
            }
        }
    __syncthreads();
    if (m16 == 0) {
#pragma unroll
        for (int ct = 0; ct < 4; ct++)
#pragma unroll
            for (int r = 0; r < 4; r++)
                red[rowpair][colbase + ct * 16 + quad * 4 + r] = psum[ct][r];
    }
    __syncthreads();
    if (t < 128) atomicAdd(&stats[(blockIdx.x & 7) * 256 + t], red[0][t] + red[1][t]);
    __syncthreads();
    if (m16 == 0) {
#pragma unroll
        for (int ct = 0; ct < 4; ct++)
#pragma unroll
            for (int r = 0; r < 4; r++)
                red[rowpair][colbase + ct * 16 + quad * 4 + r] = psq[ct][r];
    }
    __syncthreads();
    if (t < 128) atomicAdd(&stats[(blockIdx.x & 7) * 256 + 128 + t], red[0][t] + red[1][t]);
}

// ---------------------------------------------------------------------------
// Dual-matrix GEMM (SAGE, sliced A/C): Cb = bf16(A1@W1 + A2@W2 + bias).
// ---------------------------------------------------------------------------
__global__ __launch_bounds__(256) void gemm_dual_kernel(
    const unsigned short* __restrict__ A1, const unsigned short* __restrict__ A2,
    const unsigned short* __restrict__ W1t, const unsigned short* __restrict__ W2t,
    const float* __restrict__ bias, float* __restrict__ stats,
    unsigned short* __restrict__ Cb, int M, int ntiles)
{
    __shared__ float red[128];

    const int t = threadIdx.x;
    const int wave = t >> 6;
    const int lane = t & 63;
    const int m16 = lane & 15;
    const int quad = lane >> 4;
    const int k0 = quad * 8;
    const int colbase = wave * 32;

    const bf16x8 zero8 = {0, 0, 0, 0, 0, 0, 0, 0};

    bf16x8 w1f[2][4], w2f[2][4];
#pragma unroll
    for (int ct = 0; ct < 2; ct++) {
        int col = colbase + ct * 16 + m16;
#pragma unroll
        for (int kc = 0; kc < 4; kc++) {
            w1f[ct][kc] = *(const bf16x8*)(W1t + (size_t)col * 128 + kc * 32 + k0);
            w2f[ct][kc] = *(const bf16x8*)(W2t + (size_t)col * 128 + kc * 32 + k0);
        }
    }
    f32x4 bs[2];
#pragma unroll
    for (int ct = 0; ct < 2; ct++)
        bs[ct] = *(const f32x4*)(bias + colbase + ct * 16 + quad * 4);

    float psum[2][4], psq[2][4];
#pragma unroll
    for (int ct = 0; ct < 2; ct++)
#pragma unroll
        for (int r = 0; r < 4; r++) { psum[ct][r] = 0.f; psq[ct][r] = 0.f; }

    bf16x8 a1[4], a2[4], a1n[4], a2n[4];

    int tile = blockIdx.x;
    if (tile < ntiles) {
        int arow = tile * 16 + m16;
        bool aok = arow < M;
#pragma unroll
        for (int kc = 0; kc < 4; kc++) {
            size_t aoff = (size_t)(kc * 2 + (quad >> 1)) * SLICE_STRIDE
                        + (size_t)arow * 16 + (quad & 1) * 8;
            a1[kc] = aok ? *(const bf16x8*)(A1 + aoff) : zero8;
            a2[kc] = aok ? *(const bf16x8*)(A2 + aoff) : zero8;
        }
    }

    for (; tile < ntiles; tile += gridDim.x) {
        int nt = tile + gridDim.x;
        if (nt < ntiles) {
            int arow = nt * 16 + m16;
            bool aok = arow < M;
#pragma unroll
            for (int kc = 0; kc < 4; kc++) {
                size_t aoff = (size_t)(kc * 2 + (quad >> 1)) * SLICE_STRIDE
                            + (size_t)arow * 16 + (quad & 1) * 8;
                a1n[kc] = aok ? *(const bf16x8*)(A1 + aoff) : zero8;
                a2n[kc] = aok ? *(const bf16x8*)(A2 + aoff) : zero8;
            }
        }

        f32x4 acc[2];
        acc[0] = (f32x4){0.f, 0.f, 0.f, 0.f};
        acc[1] = (f32x4){0.f, 0.f, 0.f, 0.f};
#pragma unroll
        for (int kc = 0; kc < 4; kc++) {
#pragma unroll
            for (int ct = 0; ct < 2; ct++) {
                acc[ct] = __builtin_amdgcn_mfma_f32_16x16x32_bf16(w1f[ct][kc], a1[kc], acc[ct], 0, 0, 0);
                acc[ct] = __builtin_amdgcn_mfma_f32_16x16x32_bf16(w2f[ct][kc], a2[kc], acc[ct], 0, 0, 0);
            }
        }

        int orow = tile * 16 + m16;
        if (orow < M) {
#pragma unroll
            for (int ct = 0; ct < 2; ct++) {
                f32x4 v = acc[ct] + bs[ct];
#pragma unroll
                for (int r = 0; r < 4; r++) { psum[ct][r] += v[r]; psq[ct][r] += v[r] * v[r]; }
                ushort4 o;
                o.x = f2b(v[0]); o.y = f2b(v[1]); o.z = f2b(v[2]); o.w = f2b(v[3]);
                int cs = wave * 2 + ct;
                *(ushort4*)(Cb + (size_t)cs * SLICE_STRIDE + (size_t)orow * 16 + quad * 4) = o;
            }
        }

        if (nt < ntiles) {
            a1[0] = a1n[0]; a1[1] = a1n[1]; a1[2] = a1n[2]; a1[3] = a1n[3];
            a2[0] = a2n[0]; a2[1] = a2n[1]; a2[2] = a2n[2]; a2[3] = a2n[3];
        }
    }

#pragma unroll
    for (int ct = 0; ct < 2; ct++)
#pragma unroll
        for (int r = 0; r < 4; r++) {
#pragma unroll
            for (int mask = 1; mask <= 8; mask <<= 1) {
                psum[ct][r] += __shfl_xor(psum[ct][r], mask, 64);
                psq[ct][r]  += __shfl_xor(psq[ct][r], mask, 64);
            }
        }
    if (m16 == 0) {
#pragma unroll
        for (int ct = 0; ct < 2; ct++)
#pragma unroll
            for (int r = 0; r < 4; r++)
                red[colbase + ct * 16 + quad * 4 + r] = psum[ct][r];
    }
    __syncthreads();
    if (t < 128) atomicAdd(&stats[(blockIdx.x & 7) * 256 + t], red[t]);
    __syncthreads();
    if (m16 == 0) {
#pragma unroll
        for (int ct = 0; ct < 2; ct++)
#pragma unroll
            for (int r = 0; r < 4; r++)
                red[colbase + ct * 16 + quad * 4 + r] = psq[ct][r];
    }
    __syncthreads();
    if (t < 128) atomicAdd(&stats[(blockIdx.x & 7) * 256 + 128 + t], red[t]);
}

// ---------------------------------------------------------------------------
// finish: Hact = relu(bn(Hpre)); sliced layout, linear 16B/thread streaming
// ---------------------------------------------------------------------------
__global__ __launch_bounds__(256) void finish_kernel(
    const unsigned short* __restrict__ Hpre, const float* __restrict__ stats,
    const float* __restrict__ gamma, const float* __restrict__ beta,
    unsigned short* __restrict__ Hact)
{
    __shared__ float cs[2][128];
    int t = threadIdx.x;
    if (t < 128) {
        float mu = stats_sum(stats, t) * INV_N;
        float var = stats_sum(stats, 128 + t) * INV_N - mu * mu;
        float rs = rsqrtf(var + BN_EPS);
        float c = gamma[t] * rs;
        cs[0][t] = c;
        cs[1][t] = beta[t] - mu * c;
    }
    __syncthreads();
    int gid = blockIdx.x * 256 + t;          // 800000 chunks of 8 elems
    int e0 = gid * 8;
    int s = (unsigned)e0 / SLICE_STRIDE;
    int rem = e0 - s * SLICE_STRIDE;
    int col0 = s * 16 + (rem & 15);
    bf16x8 v = *(const bf16x8*)(Hpre + e0);
    bf16x8 o;
#pragma unroll
    for (int j = 0; j < 8; j++)
        o[j] = (short)f2b(fmaxf(b2f((unsigned short)v[j]) * cs[0][col0 + j] + cs[1][col0 + j], 0.f));
    *(bf16x8*)(Hact + e0) = o;
}

// ---------------------------------------------------------------------------
// global mean pool (sliced input): BN affine from stats, relu, mean.
// 256 thr: 16 row-groups x 16 col-chunks (16B/lane).
// ---------------------------------------------------------------------------
__global__ __launch_bounds__(256) void pool_mean_kernel(const unsigned short* __restrict__ h_s,
                                                        const int* __restrict__ gstart,
                                                        const float* __restrict__ stats,
                                                        const float* __restrict__ gamma,
                                                        const float* __restrict__ beta,
                                                        float* __restrict__ out) {
    __shared__ float red[16][128];
    int g = blockIdx.x;
    int t = threadIdx.x;
    int grp = t >> 4;
    int ci = t & 15;
    int c0 = ci * 8;
    float c[8], b[8];
#pragma unroll
    for (int j = 0; j < 8; j++) {
        int col = c0 + j;
        float mu = stats_sum(stats, col) * INV_N;
        float var = stats_sum(stats, 128 + col) * INV_N - mu * mu;
        float rs = rsqrtf(var + BN_EPS);
        c[j] = gamma[col] * rs;
        b[j] = beta[col] - mu * c[j];
    }
    int beg = gstart[g];
    int end = gstart[g + 1];
    float sa[8];
#pragma unroll
    for (int j = 0; j < 8; j++) sa[j] = 0.f;
    // slice = c0>>4 = ci>>1, off = (ci&1)*8
    const unsigned short* base = h_s + (size_t)(ci >> 1) * SLICE_STRIDE + (ci & 1) * 8;
    for (int i = beg + grp; i < end; i += 16) {
        bf16x8 v = *(const bf16x8*)(base + (size_t)i * 16);
#pragma unroll
        for (int j = 0; j < 8; j++)
            sa[j] += fmaxf(b2f((unsigned short)v[j]) * c[j] + b[j], 0.f);
    }
#pragma unroll
    for (int j = 0; j < 8; j++) red[grp][c0 + j] = sa[j];
    __syncthreads();
    if (t < 128) {
        float cnt = fmaxf((float)(end - beg), 1.0f);
        float tot = 0.f;
#pragma unroll
        for (int r = 0; r < 16; r++) tot += red[r][t];
        out[(size_t)g * 128 + t] = tot / cnt;
    }
}

// ---------------------------------------------------------------------------
extern "C" void kernel_launch(void* const* d_in, const int* in_sizes, int n_in,
                              void* d_out, int out_size, void* d_ws, size_t ws_size,
                              hipStream_t stream) {
    const float* x    = (const float*)d_in[0];
    const int*   ei   = (const int*)d_in[1];
    const int*   src  = ei;
    const int*   dst  = ei + N_EDGES;
    const int*   batch = (const int*)d_in[2];
    const float* gw1  = (const float*)d_in[3];
    const float* gb1  = (const float*)d_in[4];
    const float* gw2  = (const float*)d_in[5];
    const float* gb2  = (const float*)d_in[6];
    const float* swl  = (const float*)d_in[7];
    const float* sbl  = (const float*)d_in[8];
    const float* swr  = (const float*)d_in[9];
    const float* bng  = (const float*)d_in[10];
    const float* bnb  = (const float*)d_in[11];
    float* out = (float*)d_out;

    // workspace layout (float units; bf16 buffers 16B-aligned)
    float* ws = (float*)d_ws;
    unsigned short* x16_s  = (unsigned short*)(ws + 0);         // sliced [8][50000][16]
    unsigned short* agg_s  = (unsigned short*)(ws + 3200000);
    unsigned short* hact_s = (unsigned short*)(ws + 6400000);
    unsigned short* hpre_s = (unsigned short*)(ws + 9600000);
    unsigned short* wt     = (unsigned short*)(ws + 12800000);  // 6*16384 u16
    float*          inv_deg= ws + 12850000;                     // 50000
    int*            row_beg= (int*)(ws + 12900000);             // 50000
    int*            cursor = (int*)(ws + 12950000);             // 50000 | total | stats(3*8*256)
    int*            total  = cursor + 50000;
    float*          stats  = (float*)(cursor + 50001);          // 3 layers x 8 replicas x 256
    unsigned short* csr_src= (unsigned short*)(ws + 13100000);  // 600000 u16
    int*            gstart = (int*)(ws + 13700000);             // 513

    const int ggrid = 512;
    const int ntiles32 = (N_NODES + 31) / 32;                   // 1563
    const int ntiles16 = (N_NODES + 15) / 16;                   // 3125
    const int gather_grid = GATHER_GROUPS * NSLICES;            // 3128

    // ---- init: cursor + total + stats in one memset ----
    hipMemsetAsync(cursor, 0, (50001 + 3 * 8 * 256) * sizeof(int), stream);

    // ---- prep: x->bf16 sliced, weights->bf16^T, degree count ----
    prep_kernel<<<CONVX_BLOCKS + WCONV_BLOCKS + DEG_BLOCKS, 256, 0, stream>>>(
        x, gw1, gw2, swl, swr, dst, x16_s, wt, cursor);

    // ---- CSR ----
    alloc_kernel<<<ALLOC_BLOCKS + 3, 256, 0, stream>>>(cursor, row_beg, inv_deg, total, batch, gstart);
    csr_fill_kernel<<<(N_EDGES + 255) / 256, 256, 0, stream>>>(src, dst, cursor, csr_src, N_EDGES);

    // ---- GIN ----
    gather_slice_kernel<false><<<gather_grid, 256, 0, stream>>>(
        x16_s, row_beg, cursor, csr_src, nullptr, agg_s);
    gemm_gin_kernel<<<ggrid, 256, 0, stream>>>(
        x16_s, agg_s, wt + 0 * 16384, wt + 1 * 16384, gb1, gb2,
        stats + 0 * 2048, hpre_s, N_NODES, ntiles32);
    finish_kernel<<<3125, 256, 0, stream>>>(
        hpre_s, stats + 0 * 2048, bng + 0 * HID, bnb + 0 * HID, hact_s);

    // ---- SAGE 0 ----
    gather_slice_kernel<true><<<gather_grid, 256, 0, stream>>>(
        hact_s, row_beg, cursor, csr_src, inv_deg, agg_s);
    gemm_dual_kernel<<<ggrid, 256, 0, stream>>>(
        agg_s, hact_s, wt + 2 * 16384, wt + 3 * 16384, sbl + 0 * HID,
        stats + 1 * 2048, hpre_s, N_NODES, ntiles16);
    finish_kernel<<<3125, 256, 0, stream>>>(
        hpre_s, stats + 1 * 2048, bng + 1 * HID, bnb + 1 * HID, hact_s);

    // ---- SAGE 1 ----
    gather_slice_kernel<true><<<gather_grid, 256, 0, stream>>>(
        hact_s, row_beg, cursor, csr_src, inv_deg, agg_s);
    gemm_dual_kernel<<<ggrid, 256, 0, stream>>>(
        agg_s, hact_s, wt + 4 * 16384, wt + 5 * 16384, sbl + 1 * HID,
        stats + 2 * 2048, hpre_s, N_NODES, ntiles16);

    // ---- pool (BN2 affine folded) ----
    pool_mean_kernel<<<N_GRAPHS, 256, 0, stream>>>(
        hpre_s, gstart, stats + 2 * 2048, bng + 2 * HID, bnb + 2 * HID, out);
}

// Round 9
// 318.216 us; speedup vs baseline: 1.1073x; 1.0601x over previous
//
#include <hip/hip_runtime.h>

#define N_NODES 50000
#define N_EDGES 600000
#define HID 128
#define N_GRAPHS 512
#define BN_EPS 1e-5f
#define INV_N (1.0f / 50000.0f)
#define SLICE_STRIDE 800000     // 50000 * 16 u16 elems per column-slice
#define NSLICES 8
#define GATHER_GROUPS 391       // ceil(50000/128)
#define IDXCAP 4096

typedef __attribute__((ext_vector_type(8))) short bf16x8;
typedef __attribute__((ext_vector_type(4))) float f32x4;

__device__ __forceinline__ unsigned short f2b(float f) {
    unsigned u = __float_as_uint(f);
    return (unsigned short)((u + 0x7FFFu + ((u >> 16) & 1u)) >> 16);
}
__device__ __forceinline__ float b2f(unsigned short h) {
    return __uint_as_float(((unsigned)h) << 16);
}

// sum the 8 stats replicas
__device__ __forceinline__ float stats_sum(const float* __restrict__ s, int idx) {
    float v = 0.f;
#pragma unroll
    for (int r = 0; r < 8; r++) v += s[r * 256 + idx];
    return v;
}

// ---------------------------------------------------------------------------
// prep: x -> bf16 (16-col sliced, SLICE-PINNED: block b&7 = slice -> its
// writes land in the same XCD L2 that the GIN gather will read from)
// | transpose+convert 6 weight mats | degree count
// ---------------------------------------------------------------------------
#define CONVX_BLOCKS 6256       // 8 slices * 782 groups of 64 nodes
#define WCONV_BLOCKS 384
#define DEG_BLOCKS   2344
__global__ __launch_bounds__(256) void prep_kernel(
    const float* __restrict__ x, const float* __restrict__ gw1, const float* __restrict__ gw2,
    const float* __restrict__ swl, const float* __restrict__ swr, const int* __restrict__ dst,
    unsigned short* __restrict__ x16, unsigned short* __restrict__ wt, int* __restrict__ deg)
{
    int b = blockIdx.x;
    int t = threadIdx.x;
    if (b < CONVX_BLOCKS) {
        int s = b & 7;
        int node = (b >> 3) * 64 + (t >> 2);
        if (node >= N_NODES) return;
        int q = t & 3;
        float4 v = *(const float4*)(x + (size_t)node * 128 + s * 16 + q * 4);
        ushort4 o;
        o.x = f2b(v.x); o.y = f2b(v.y); o.z = f2b(v.z); o.w = f2b(v.w);
        *(ushort4*)(x16 + (size_t)s * SLICE_STRIDE + (size_t)node * 16 + q * 4) = o;
    } else if (b < CONVX_BLOCKS + WCONV_BLOCKS) {
        int gid = (b - CONVX_BLOCKS) * 256 + t;   // < 6*16384
        int m = gid >> 14;
        int e = gid & 16383;
        int k = e >> 7;
        int n = e & 127;
        const float* src = (m == 0) ? gw1 : (m == 1) ? gw2 : (m == 2) ? swl
                         : (m == 3) ? swr : (m == 4) ? (swl + 16384) : (swr + 16384);
        wt[m * 16384 + n * 128 + k] = f2b(src[k * 128 + n]);
    } else {
        int e = (b - CONVX_BLOCKS - WCONV_BLOCKS) * 256 + t;
        if (e < N_EDGES) atomicAdd(&deg[dst[e]], 1);
    }
}

// ---------------------------------------------------------------------------
// alloc (per-block scan + atomic base) + gstart (binary search), fused
// ---------------------------------------------------------------------------
#define ALLOC_BLOCKS 196
__global__ __launch_bounds__(256) void alloc_kernel(int* __restrict__ cursor,
                                                    int* __restrict__ row_beg,
                                                    float* __restrict__ inv_deg,
                                                    int* __restrict__ total,
                                                    const int* __restrict__ batch,
                                                    int* __restrict__ gstart) {
    if (blockIdx.x >= ALLOC_BLOCKS) {
        int g = (blockIdx.x - ALLOC_BLOCKS) * 256 + threadIdx.x;
        if (g > N_GRAPHS) return;
        int lo = 0, hi = N_NODES;
        while (lo < hi) {
            int mid = (lo + hi) >> 1;
            if (batch[mid] < g) lo = mid + 1; else hi = mid;
        }
        gstart[g] = lo;
        return;
    }
    __shared__ int tmp[256];
    __shared__ int base;
    int i = blockIdx.x * 256 + threadIdx.x;
    int d = (i < N_NODES) ? cursor[i] : 0;
    tmp[threadIdx.x] = d;
    __syncthreads();
#pragma unroll
    for (int off = 1; off < 256; off <<= 1) {
        int v = (threadIdx.x >= off) ? tmp[threadIdx.x - off] : 0;
        __syncthreads();
        tmp[threadIdx.x] += v;
        __syncthreads();
    }
    if (threadIdx.x == 255) base = atomicAdd(total, tmp[255]);
    __syncthreads();
    if (i < N_NODES) {
        int b = base + tmp[threadIdx.x] - d;
        row_beg[i] = b;
        cursor[i] = b;
        inv_deg[i] = 1.0f / fmaxf((float)d, 1.0f);
    }
}

__global__ void csr_fill_kernel(const int* __restrict__ src, const int* __restrict__ dst,
                                int* __restrict__ cursor, unsigned short* __restrict__ csr_src, int nE) {
    int e = blockIdx.x * blockDim.x + threadIdx.x;
    if (e < nE) {
        int pos = atomicAdd(&cursor[dst[e]], 1);
        csr_src[pos] = (unsigned short)src[e];
    }
}

// ---------------------------------------------------------------------------
// XCD-sliced gather: block = (group of 128 nodes, slice of 16 cols).
// slice = blockIdx & 7 -> round-robin pins each slice to one XCD; its L2
// holds the 1.6 MB slice + 1.6 MB agg writes (3.2 MB < 4 MB). 2 lanes/node,
// 16B loads, 8-deep unroll. MEAN: scale by inv_deg. (R4-verified body.)
// ---------------------------------------------------------------------------
template<bool MEAN>
__global__ __launch_bounds__(256) void gather_slice_kernel(
    const unsigned short* __restrict__ feat_s,
    const int* __restrict__ row_beg, const int* __restrict__ row_end,
    const unsigned short* __restrict__ csr_src,
    const float* __restrict__ inv_deg,
    unsigned short* __restrict__ out_s)
{
    __shared__ unsigned short idxbuf[IDXCAP];
    const int t = threadIdx.x;
    const int slice = blockIdx.x & 7;
    const int grp = blockIdx.x >> 3;
    const int node0 = grp * 128;
    const int nlast = (node0 + 127 < N_NODES) ? node0 + 127 : N_NODES - 1;
    const int node = node0 + (t >> 1);
    const int l8 = (t & 1) * 8;
    const unsigned short* fbase = feat_s + (size_t)slice * SLICE_STRIDE + l8;

    const int ebeg = row_beg[node0];
    const int ecnt = row_end[nlast] - ebeg;
    const bool lds_ok = (ecnt <= IDXCAP);
    if (lds_ok)
        for (int i = t; i < ecnt; i += 256) idxbuf[i] = csr_src[ebeg + i];
    __syncthreads();
    if (node >= N_NODES) return;

    const int beg = row_beg[node];
    const int deg = row_end[node] - beg;

    float a[8];
#pragma unroll
    for (int j = 0; j < 8; j++) a[j] = 0.f;

    if (lds_ok) {
        const int off = beg - ebeg;
        int e = 0;
        for (; e + 7 < deg; e += 8) {
            int s[8];
#pragma unroll
            for (int u = 0; u < 8; u++) s[u] = idxbuf[off + e + u];
            bf16x8 v[8];
#pragma unroll
            for (int u = 0; u < 8; u++)
                v[u] = *(const bf16x8*)(fbase + (size_t)s[u] * 16);
#pragma unroll
            for (int u = 0; u < 8; u++)
#pragma unroll
                for (int j = 0; j < 8; j++)
                    a[j] += b2f((unsigned short)v[u][j]);
        }
        for (; e + 3 < deg; e += 4) {
            int s[4];
#pragma unroll
            for (int u = 0; u < 4; u++) s[u] = idxbuf[off + e + u];
            bf16x8 v[4];
#pragma unroll
            for (int u = 0; u < 4; u++)
                v[u] = *(const bf16x8*)(fbase + (size_t)s[u] * 16);
#pragma unroll
            for (int u = 0; u < 4; u++)
#pragma unroll
                for (int j = 0; j < 8; j++)
                    a[j] += b2f((unsigned short)v[u][j]);
        }
        for (; e < deg; e++) {
            int s0 = idxbuf[off + e];
            bf16x8 v0 = *(const bf16x8*)(fbase + (size_t)s0 * 16);
#pragma unroll
            for (int j = 0; j < 8; j++)
                a[j] += b2f((unsigned short)v0[j]);
        }
    } else {
        // pathological skew fallback
        for (int e = beg; e < beg + deg; e++) {
            int s0 = csr_src[e];
            bf16x8 v0 = *(const bf16x8*)(fbase + (size_t)s0 * 16);
#pragma unroll
            for (int j = 0; j < 8; j++)
                a[j] += b2f((unsigned short)v0[j]);
        }
    }

    if (MEAN) {
        float sc = inv_deg[node];
#pragma unroll
        for (int j = 0; j < 8; j++) a[j] *= sc;
    }
    bf16x8 o;
#pragma unroll
    for (int j = 0; j < 8; j++) o[j] = (short)f2b(a[j]);
    *(bf16x8*)(out_s + (size_t)slice * SLICE_STRIDE + (size_t)node * 16 + l8) = o;
}

// ---------------------------------------------------------------------------
// Fused GIN GEMM (sliced A/C): Cb = bf16( relu((X+AGG)@W1+b1) @ W2 + b2 ).
// Weights register-stationary; T1 via 32x136 LDS tile. Stats 8-replica.
// ---------------------------------------------------------------------------
__global__ __launch_bounds__(256, 2) void gemm_gin_kernel(
    const unsigned short* __restrict__ X, const unsigned short* __restrict__ AGG,
    const unsigned short* __restrict__ W1t, const unsigned short* __restrict__ W2t,
    const float* __restrict__ b1, const float* __restrict__ b2,
    float* __restrict__ stats, unsigned short* __restrict__ Cb,
    int M, int ntiles)
{
    __shared__ unsigned short t1[32][136];
    __shared__ float red[2][128];

    const int t = threadIdx.x;
    const int wave = t >> 6;
    const int lane = t & 63;
    const int colhalf = wave & 1;
    const int rowpair = wave >> 1;
    const int m16 = lane & 15;
    const int quad = lane >> 4;
    const int k0 = quad * 8;
    const int colbase = colhalf * 64;
    const int lrow = rowpair * 16 + m16;

    const bf16x8 zero8 = {0, 0, 0, 0, 0, 0, 0, 0};

    bf16x8 w1f[4][4], w2f[4][4];
#pragma unroll
    for (int ct = 0; ct < 4; ct++) {
        int col = colbase + ct * 16 + m16;
#pragma unroll
        for (int kc = 0; kc < 4; kc++) {
            w1f[ct][kc] = *(const bf16x8*)(W1t + (size_t)col * 128 + kc * 32 + k0);
            w2f[ct][kc] = *(const bf16x8*)(W2t + (size_t)col * 128 + kc * 32 + k0);
        }
    }
    f32x4 bs1[4], bs2[4];
#pragma unroll
    for (int ct = 0; ct < 4; ct++) {
        bs1[ct] = *(const f32x4*)(b1 + colbase + ct * 16 + quad * 4);
        bs2[ct] = *(const f32x4*)(b2 + colbase + ct * 16 + quad * 4);
    }

    float psum[4][4], psq[4][4];
#pragma unroll
    for (int ct = 0; ct < 4; ct++)
#pragma unroll
        for (int r = 0; r < 4; r++) { psum[ct][r] = 0.f; psq[ct][r] = 0.f; }

    for (int tile = blockIdx.x; tile < ntiles; tile += gridDim.x) {
        int arow = tile * 32 + rowpair * 16 + m16;
        bool aok = arow < M;

        // A = bf16(x + agg); col = kc*32 + quad*8 -> slice = 2*kc + (quad>>1)
        bf16x8 a[4];
#pragma unroll
        for (int kc = 0; kc < 4; kc++) {
            if (aok) {
                size_t aoff = (size_t)(kc * 2 + (quad >> 1)) * SLICE_STRIDE
                            + (size_t)arow * 16 + (quad & 1) * 8;
                bf16x8 vx = *(const bf16x8*)(X + aoff);
                bf16x8 vg = *(const bf16x8*)(AGG + aoff);
                bf16x8 r;
#pragma unroll
                for (int i = 0; i < 8; i++)
                    r[i] = (short)f2b(b2f((unsigned short)vx[i]) + b2f((unsigned short)vg[i]));
                a[kc] = r;
            } else {
                a[kc] = zero8;
            }
        }

        // phase 1
        f32x4 acc[4];
#pragma unroll
        for (int ct = 0; ct < 4; ct++) acc[ct] = (f32x4){0.f, 0.f, 0.f, 0.f};
#pragma unroll
        for (int kc = 0; kc < 4; kc++)
#pragma unroll
            for (int ct = 0; ct < 4; ct++)
                acc[ct] = __builtin_amdgcn_mfma_f32_16x16x32_bf16(w1f[ct][kc], a[kc], acc[ct], 0, 0, 0);

        __syncthreads();   // previous tile's t1 reads done
#pragma unroll
        for (int ct = 0; ct < 4; ct++) {
            f32x4 v = acc[ct] + bs1[ct];
            ushort4 o;
            o.x = f2b(fmaxf(v[0], 0.f));
            o.y = f2b(fmaxf(v[1], 0.f));
            o.z = f2b(fmaxf(v[2], 0.f));
            o.w = f2b(fmaxf(v[3], 0.f));
            *(ushort4*)&t1[lrow][colbase + ct * 16 + quad * 4] = o;
        }
        __syncthreads();

        // phase 2
        bf16x8 ta[4];
#pragma unroll
        for (int kc = 0; kc < 4; kc++)
            ta[kc] = *(const bf16x8*)&t1[lrow][kc * 32 + k0];

        f32x4 acc2[4];
#pragma unroll
        for (int ct = 0; ct < 4; ct++) acc2[ct] = (f32x4){0.f, 0.f, 0.f, 0.f};
#pragma unroll
        for (int kc = 0; kc < 4; kc++)
#pragma unroll
            for (int ct = 0; ct < 4; ct++)
                acc2[ct] = __builtin_amdgcn_mfma_f32_16x16x32_bf16(w2f[ct][kc], ta[kc], acc2[ct], 0, 0, 0);

        if (arow < M) {
#pragma unroll
            for (int ct = 0; ct < 4; ct++) {
                f32x4 v = acc2[ct] + bs2[ct];
#pragma unroll
                for (int r = 0; r < 4; r++) { psum[ct][r] += v[r]; psq[ct][r] += v[r] * v[r]; }
                ushort4 o;
                o.x = f2b(v[0]); o.y = f2b(v[1]); o.z = f2b(v[2]); o.w = f2b(v[3]);
                int cs = (colbase >> 4) + ct;
                *(ushort4*)(Cb + (size_t)cs * SLICE_STRIDE + (size_t)arow * 16 + quad * 4) = o;
            }
        }
    }

    // stats flush (8-replica)
#pragma unroll
    for (int ct = 0; ct < 4; ct++)
#pragma unroll
        for (int r = 0; r < 4; r++) {
#pragma unroll
            for (int mask = 1; mask <= 8; mask <<= 1) {
                psum[ct][r] += __shfl_xor(psum[ct][r], mask, 64);
                psq[ct][r]  += __shfl_xor(psq[ct][r], mask, 64);
            }
        }
    __syncthreads();
    if (m16 == 0) {
#pragma unroll
        for (int ct = 0; ct < 4; ct++)
#pragma unroll
            for (int r = 0; r < 4; r++)
                red[rowpair][colbase + ct * 16 + quad * 4 + r] = psum[ct][r];
    }
    __syncthreads();
    if (t < 128) atomicAdd(&stats[(blockIdx.x & 7) * 256 + t], red[0][t] + red[1][t]);
    __syncthreads();
    if (m16 == 0) {
#pragma unroll
        for (int ct = 0; ct < 4; ct++)
#pragma unroll
            for (int r = 0; r < 4; r++)
                red[rowpair][colbase + ct * 16 + quad * 4 + r] = psq[ct][r];
    }
    __syncthreads();
    if (t < 128) atomicAdd(&stats[(blockIdx.x & 7) * 256 + 128 + t], red[0][t] + red[1][t]);
}

// ---------------------------------------------------------------------------
// Dual-matrix GEMM (SAGE, sliced A/C): Cb = bf16(A1@W1 + A2@W2 + bias).
// ---------------------------------------------------------------------------
__global__ __launch_bounds__(256) void gemm_dual_kernel(
    const unsigned short* __restrict__ A1, const unsigned short* __restrict__ A2,
    const unsigned short* __restrict__ W1t, const unsigned short* __restrict__ W2t,
    const float* __restrict__ bias, float* __restrict__ stats,
    unsigned short* __restrict__ Cb, int M, int ntiles)
{
    __shared__ float red[128];

    const int t = threadIdx.x;
    const int wave = t >> 6;
    const int lane = t & 63;
    const int m16 = lane & 15;
    const int quad = lane >> 4;
    const int k0 = quad * 8;
    const int colbase = wave * 32;

    const bf16x8 zero8 = {0, 0, 0, 0, 0, 0, 0, 0};

    bf16x8 w1f[2][4], w2f[2][4];
#pragma unroll
    for (int ct = 0; ct < 2; ct++) {
        int col = colbase + ct * 16 + m16;
#pragma unroll
        for (int kc = 0; kc < 4; kc++) {
            w1f[ct][kc] = *(const bf16x8*)(W1t + (size_t)col * 128 + kc * 32 + k0);
            w2f[ct][kc] = *(const bf16x8*)(W2t + (size_t)col * 128 + kc * 32 + k0);
        }
    }
    f32x4 bs[2];
#pragma unroll
    for (int ct = 0; ct < 2; ct++)
        bs[ct] = *(const f32x4*)(bias + colbase + ct * 16 + quad * 4);

    float psum[2][4], psq[2][4];
#pragma unroll
    for (int ct = 0; ct < 2; ct++)
#pragma unroll
        for (int r = 0; r < 4; r++) { psum[ct][r] = 0.f; psq[ct][r] = 0.f; }

    bf16x8 a1[4], a2[4], a1n[4], a2n[4];

    int tile = blockIdx.x;
    if (tile < ntiles) {
        int arow = tile * 16 + m16;
        bool aok = arow < M;
#pragma unroll
        for (int kc = 0; kc < 4; kc++) {
            size_t aoff = (size_t)(kc * 2 + (quad >> 1)) * SLICE_STRIDE
                        + (size_t)arow * 16 + (quad & 1) * 8;
            a1[kc] = aok ? *(const bf16x8*)(A1 + aoff) : zero8;
            a2[kc] = aok ? *(const bf16x8*)(A2 + aoff) : zero8;
        }
    }

    for (; tile < ntiles; tile += gridDim.x) {
        int nt = tile + gridDim.x;
        if (nt < ntiles) {
            int arow = nt * 16 + m16;
            bool aok = arow < M;
#pragma unroll
            for (int kc = 0; kc < 4; kc++) {
                size_t aoff = (size_t)(kc * 2 + (quad >> 1)) * SLICE_STRIDE
                            + (size_t)arow * 16 + (quad & 1) * 8;
                a1n[kc] = aok ? *(const bf16x8*)(A1 + aoff) : zero8;
                a2n[kc] = aok ? *(const bf16x8*)(A2 + aoff) : zero8;
            }
        }

        f32x4 acc[2];
        acc[0] = (f32x4){0.f, 0.f, 0.f, 0.f};
        acc[1] = (f32x4){0.f, 0.f, 0.f, 0.f};
#pragma unroll
        for (int kc = 0; kc < 4; kc++) {
#pragma unroll
            for (int ct = 0; ct < 2; ct++) {
                acc[ct] = __builtin_amdgcn_mfma_f32_16x16x32_bf16(w1f[ct][kc], a1[kc], acc[ct], 0, 0, 0);
                acc[ct] = __builtin_amdgcn_mfma_f32_16x16x32_bf16(w2f[ct][kc], a2[kc], acc[ct], 0, 0, 0);
            }
        }

        int orow = tile * 16 + m16;
        if (orow < M) {
#pragma unroll
            for (int ct = 0; ct < 2; ct++) {
                f32x4 v = acc[ct] + bs[ct];
#pragma unroll
                for (int r = 0; r < 4; r++) { psum[ct][r] += v[r]; psq[ct][r] += v[r] * v[r]; }
                ushort4 o;
                o.x = f2b(v[0]); o.y = f2b(v[1]); o.z = f2b(v[2]); o.w = f2b(v[3]);
                int cs = wave * 2 + ct;
                *(ushort4*)(Cb + (size_t)cs * SLICE_STRIDE + (size_t)orow * 16 + quad * 4) = o;
            }
        }

        if (nt < ntiles) {
            a1[0] = a1n[0]; a1[1] = a1n[1]; a1[2] = a1n[2]; a1[3] = a1n[3];
            a2[0] = a2n[0]; a2[1] = a2n[1]; a2[2] = a2n[2]; a2[3] = a2n[3];
        }
    }

#pragma unroll
    for (int ct = 0; ct < 2; ct++)
#pragma unroll
        for (int r = 0; r < 4; r++) {
#pragma unroll
            for (int mask = 1; mask <= 8; mask <<= 1) {
                psum[ct][r] += __shfl_xor(psum[ct][r], mask, 64);
                psq[ct][r]  += __shfl_xor(psq[ct][r], mask, 64);
            }
        }
    if (m16 == 0) {
#pragma unroll
        for (int ct = 0; ct < 2; ct++)
#pragma unroll
            for (int r = 0; r < 4; r++)
                red[colbase + ct * 16 + quad * 4 + r] = psum[ct][r];
    }
    __syncthreads();
    if (t < 128) atomicAdd(&stats[(blockIdx.x & 7) * 256 + t], red[t]);
    __syncthreads();
    if (m16 == 0) {
#pragma unroll
        for (int ct = 0; ct < 2; ct++)
#pragma unroll
            for (int r = 0; r < 4; r++)
                red[colbase + ct * 16 + quad * 4 + r] = psq[ct][r];
    }
    __syncthreads();
    if (t < 128) atomicAdd(&stats[(blockIdx.x & 7) * 256 + 128 + t], red[t]);
}

// ---------------------------------------------------------------------------
// finish: Hact = relu(bn(Hpre)); SLICE-PINNED (block b&7 = slice) so hact
// writes land in the XCD whose gather will read them. Streaming 16B/thread.
// ---------------------------------------------------------------------------
__global__ __launch_bounds__(256) void finish_kernel(
    const unsigned short* __restrict__ Hpre, const float* __restrict__ stats,
    const float* __restrict__ gamma, const float* __restrict__ beta,
    unsigned short* __restrict__ Hact)
{
    __shared__ float cs[2][16];
    int t = threadIdx.x;
    int s = blockIdx.x & 7;
    int nb = blockIdx.x >> 3;
    if (t < 16) {
        int col = s * 16 + t;
        float mu = stats_sum(stats, col) * INV_N;
        float var = stats_sum(stats, 128 + col) * INV_N - mu * mu;
        float rs = rsqrtf(var + BN_EPS);
        float c = gamma[col] * rs;
        cs[0][t] = c;
        cs[1][t] = beta[col] - mu * c;
    }
    __syncthreads();
    int chunk = nb * 256 + t;               // 8-elem chunk within slice
    if (chunk >= 100000) return;            // 800000 / 8
    int l8 = (chunk & 1) * 8;               // col offset within 16-col row
    size_t e0 = (size_t)s * SLICE_STRIDE + (size_t)chunk * 8;
    bf16x8 v = *(const bf16x8*)(Hpre + e0);
    bf16x8 o;
#pragma unroll
    for (int j = 0; j < 8; j++)
        o[j] = (short)f2b(fmaxf(b2f((unsigned short)v[j]) * cs[0][l8 + j] + cs[1][l8 + j], 0.f));
    *(bf16x8*)(Hact + e0) = o;
}

// ---------------------------------------------------------------------------
// global mean pool (sliced input): BN affine from stats, relu, mean.
// 256 thr: 16 row-groups x 16 col-chunks (16B/lane).
// ---------------------------------------------------------------------------
__global__ __launch_bounds__(256) void pool_mean_kernel(const unsigned short* __restrict__ h_s,
                                                        const int* __restrict__ gstart,
                                                        const float* __restrict__ stats,
                                                        const float* __restrict__ gamma,
                                                        const float* __restrict__ beta,
                                                        float* __restrict__ out) {
    __shared__ float red[16][128];
    int g = blockIdx.x;
    int t = threadIdx.x;
    int grp = t >> 4;
    int ci = t & 15;
    int c0 = ci * 8;
    float c[8], b[8];
#pragma unroll
    for (int j = 0; j < 8; j++) {
        int col = c0 + j;
        float mu = stats_sum(stats, col) * INV_N;
        float var = stats_sum(stats, 128 + col) * INV_N - mu * mu;
        float rs = rsqrtf(var + BN_EPS);
        c[j] = gamma[col] * rs;
        b[j] = beta[col] - mu * c[j];
    }
    int beg = gstart[g];
    int end = gstart[g + 1];
    float sa[8];
#pragma unroll
    for (int j = 0; j < 8; j++) sa[j] = 0.f;
    // slice = c0>>4 = ci>>1, off = (ci&1)*8
    const unsigned short* base = h_s + (size_t)(ci >> 1) * SLICE_STRIDE + (ci & 1) * 8;
    for (int i = beg + grp; i < end; i += 16) {
        bf16x8 v = *(const bf16x8*)(base + (size_t)i * 16);
#pragma unroll
        for (int j = 0; j < 8; j++)
            sa[j] += fmaxf(b2f((unsigned short)v[j]) * c[j] + b[j], 0.f);
    }
#pragma unroll
    for (int j = 0; j < 8; j++) red[grp][c0 + j] = sa[j];
    __syncthreads();
    if (t < 128) {
        float cnt = fmaxf((float)(end - beg), 1.0f);
        float tot = 0.f;
#pragma unroll
        for (int r = 0; r < 16; r++) tot += red[r][t];
        out[(size_t)g * 128 + t] = tot / cnt;
    }
}

// ---------------------------------------------------------------------------
extern "C" void kernel_launch(void* const* d_in, const int* in_sizes, int n_in,
                              void* d_out, int out_size, void* d_ws, size_t ws_size,
                              hipStream_t stream) {
    const float* x    = (const float*)d_in[0];
    const int*   ei   = (const int*)d_in[1];
    const int*   src  = ei;
    const int*   dst  = ei + N_EDGES;
    const int*   batch = (const int*)d_in[2];
    const float* gw1  = (const float*)d_in[3];
    const float* gb1  = (const float*)d_in[4];
    const float* gw2  = (const float*)d_in[5];
    const float* gb2  = (const float*)d_in[6];
    const float* swl  = (const float*)d_in[7];
    const float* sbl  = (const float*)d_in[8];
    const float* swr  = (const float*)d_in[9];
    const float* bng  = (const float*)d_in[10];
    const float* bnb  = (const float*)d_in[11];
    float* out = (float*)d_out;

    // workspace layout (float units; bf16 buffers 16B-aligned)
    float* ws = (float*)d_ws;
    unsigned short* x16_s  = (unsigned short*)(ws + 0);         // sliced [8][50000][16]
    unsigned short* agg_s  = (unsigned short*)(ws + 3200000);
    unsigned short* hact_s = (unsigned short*)(ws + 6400000);
    unsigned short* hpre_s = (unsigned short*)(ws + 9600000);
    unsigned short* wt     = (unsigned short*)(ws + 12800000);  // 6*16384 u16
    float*          inv_deg= ws + 12850000;                     // 50000
    int*            row_beg= (int*)(ws + 12900000);             // 50000
    int*            cursor = (int*)(ws + 12950000);             // 50000 | total | stats(3*8*256)
    int*            total  = cursor + 50000;
    float*          stats  = (float*)(cursor + 50001);          // 3 layers x 8 replicas x 256
    unsigned short* csr_src= (unsigned short*)(ws + 13100000);  // 600000 u16
    int*            gstart = (int*)(ws + 13700000);             // 513

    const int ggrid = 512;
    const int ntiles32 = (N_NODES + 31) / 32;                   // 1563
    const int ntiles16 = (N_NODES + 15) / 16;                   // 3125
    const int gather_grid = GATHER_GROUPS * NSLICES;            // 3128
    const int finish_grid = 391 * NSLICES;                      // 3128 (slice-pinned)

    // ---- init: cursor + total + stats in one memset ----
    hipMemsetAsync(cursor, 0, (50001 + 3 * 8 * 256) * sizeof(int), stream);

    // ---- prep: x->bf16 sliced (slice-pinned), weights->bf16^T, degree ----
    prep_kernel<<<CONVX_BLOCKS + WCONV_BLOCKS + DEG_BLOCKS, 256, 0, stream>>>(
        x, gw1, gw2, swl, swr, dst, x16_s, wt, cursor);

    // ---- CSR ----
    alloc_kernel<<<ALLOC_BLOCKS + 3, 256, 0, stream>>>(cursor, row_beg, inv_deg, total, batch, gstart);
    csr_fill_kernel<<<(N_EDGES + 255) / 256, 256, 0, stream>>>(src, dst, cursor, csr_src, N_EDGES);

    // ---- GIN ----
    gather_slice_kernel<false><<<gather_grid, 256, 0, stream>>>(
        x16_s, row_beg, cursor, csr_src, nullptr, agg_s);
    gemm_gin_kernel<<<ggrid, 256, 0, stream>>>(
        x16_s, agg_s, wt + 0 * 16384, wt + 1 * 16384, gb1, gb2,
        stats + 0 * 2048, hpre_s, N_NODES, ntiles32);
    finish_kernel<<<finish_grid, 256, 0, stream>>>(
        hpre_s, stats + 0 * 2048, bng + 0 * HID, bnb + 0 * HID, hact_s);

    // ---- SAGE 0 ----
    gather_slice_kernel<true><<<gather_grid, 256, 0, stream>>>(
        hact_s, row_beg, cursor, csr_src, inv_deg, agg_s);
    gemm_dual_kernel<<<ggrid, 256, 0, stream>>>(
        agg_s, hact_s, wt + 2 * 16384, wt + 3 * 16384, sbl + 0 * HID,
        stats + 1 * 2048, hpre_s, N_NODES, ntiles16);
    finish_kernel<<<finish_grid, 256, 0, stream>>>(
        hpre_s, stats + 1 * 2048, bng + 1 * HID, bnb + 1 * HID, hact_s);

    // ---- SAGE 1 ----
    gather_slice_kernel<true><<<gather_grid, 256, 0, stream>>>(
        hact_s, row_beg, cursor, csr_src, inv_deg, agg_s);
    gemm_dual_kernel<<<ggrid, 256, 0, stream>>>(
        agg_s, hact_s, wt + 4 * 16384, wt + 5 * 16384, sbl + 1 * HID,
        stats + 2 * 2048, hpre_s, N_NODES, ntiles16);

    // ---- pool (BN2 affine folded) ----
    pool_mean_kernel<<<N_GRAPHS, 256, 0, stream>>>(
        hpre_s, gstart, stats + 2 * 2048, bng + 2 * HID, bnb + 2 * HID, out);
}

// Round 10
// 315.500 us; speedup vs baseline: 1.1168x; 1.0086x over previous
//
#include <hip/hip_runtime.h>

#define N_NODES 50000
#define N_EDGES 600000
#define HID 128
#define N_GRAPHS 512
#define BN_EPS 1e-5f
#define INV_N (1.0f / 50000.0f)
#define SLICE_STRIDE 800000     // 50000 * 16 u16 elems per column-slice
#define NSLICES 8
#define GATHER_GROUPS 391       // ceil(50000/128)
#define IDXCAP 4096

typedef __attribute__((ext_vector_type(8))) short bf16x8;
typedef __attribute__((ext_vector_type(4))) float f32x4;

__device__ __forceinline__ unsigned short f2b(float f) {
    unsigned u = __float_as_uint(f);
    return (unsigned short)((u + 0x7FFFu + ((u >> 16) & 1u)) >> 16);
}
__device__ __forceinline__ float b2f(unsigned short h) {
    return __uint_as_float(((unsigned)h) << 16);
}

// sum the 8 stats replicas
__device__ __forceinline__ float stats_sum(const float* __restrict__ s, int idx) {
    float v = 0.f;
#pragma unroll
    for (int r = 0; r < 8; r++) v += s[r * 256 + idx];
    return v;
}

// ---------------------------------------------------------------------------
// prep: x -> bf16 (16-col sliced) | transpose+convert 6 weight mats | degree
// ---------------------------------------------------------------------------
#define CONVX_BLOCKS 6250
#define WCONV_BLOCKS 384
#define DEG_BLOCKS   2344
__global__ __launch_bounds__(256) void prep_kernel(
    const float* __restrict__ x, const float* __restrict__ gw1, const float* __restrict__ gw2,
    const float* __restrict__ swl, const float* __restrict__ swr, const int* __restrict__ dst,
    unsigned short* __restrict__ x16, unsigned short* __restrict__ wt, int* __restrict__ deg)
{
    int b = blockIdx.x;
    int t = threadIdx.x;
    if (b < CONVX_BLOCKS) {
        int gid = b * 256 + t;
        int i = gid >> 5, l = gid & 31;
        if (i >= N_NODES) return;
        int c0 = l * 4;
        float4 v = *(const float4*)(x + (size_t)i * 128 + c0);
        ushort4 o;
        o.x = f2b(v.x); o.y = f2b(v.y); o.z = f2b(v.z); o.w = f2b(v.w);
        // sliced: slice = c0>>4 = l>>2 ; off = c0&15 = (l&3)*4
        *(ushort4*)(x16 + (size_t)(l >> 2) * SLICE_STRIDE + (size_t)i * 16 + (l & 3) * 4) = o;
    } else if (b < CONVX_BLOCKS + WCONV_BLOCKS) {
        int gid = (b - CONVX_BLOCKS) * 256 + t;   // < 6*16384
        int m = gid >> 14;
        int e = gid & 16383;
        int k = e >> 7;
        int n = e & 127;
        const float* src = (m == 0) ? gw1 : (m == 1) ? gw2 : (m == 2) ? swl
                         : (m == 3) ? swr : (m == 4) ? (swl + 16384) : (swr + 16384);
        wt[m * 16384 + n * 128 + k] = f2b(src[k * 128 + n]);
    } else {
        int e = (b - CONVX_BLOCKS - WCONV_BLOCKS) * 256 + t;
        if (e < N_EDGES) atomicAdd(&deg[dst[e]], 1);
    }
}

// ---------------------------------------------------------------------------
// alloc (per-block scan + atomic base) + gstart (binary search), fused
// ---------------------------------------------------------------------------
#define ALLOC_BLOCKS 196
__global__ __launch_bounds__(256) void alloc_kernel(int* __restrict__ cursor,
                                                    int* __restrict__ row_beg,
                                                    float* __restrict__ inv_deg,
                                                    int* __restrict__ total,
                                                    const int* __restrict__ batch,
                                                    int* __restrict__ gstart) {
    if (blockIdx.x >= ALLOC_BLOCKS) {
        int g = (blockIdx.x - ALLOC_BLOCKS) * 256 + threadIdx.x;
        if (g > N_GRAPHS) return;
        int lo = 0, hi = N_NODES;
        while (lo < hi) {
            int mid = (lo + hi) >> 1;
            if (batch[mid] < g) lo = mid + 1; else hi = mid;
        }
        gstart[g] = lo;
        return;
    }
    __shared__ int tmp[256];
    __shared__ int base;
    int i = blockIdx.x * 256 + threadIdx.x;
    int d = (i < N_NODES) ? cursor[i] : 0;
    tmp[threadIdx.x] = d;
    __syncthreads();
#pragma unroll
    for (int off = 1; off < 256; off <<= 1) {
        int v = (threadIdx.x >= off) ? tmp[threadIdx.x - off] : 0;
        __syncthreads();
        tmp[threadIdx.x] += v;
        __syncthreads();
    }
    if (threadIdx.x == 255) base = atomicAdd(total, tmp[255]);
    __syncthreads();
    if (i < N_NODES) {
        int b = base + tmp[threadIdx.x] - d;
        row_beg[i] = b;
        cursor[i] = b;
        inv_deg[i] = 1.0f / fmaxf((float)d, 1.0f);
    }
}

__global__ void csr_fill_kernel(const int* __restrict__ src, const int* __restrict__ dst,
                                int* __restrict__ cursor, unsigned short* __restrict__ csr_src, int nE) {
    int e = blockIdx.x * blockDim.x + threadIdx.x;
    if (e < nE) {
        int pos = atomicAdd(&cursor[dst[e]], 1);
        csr_src[pos] = (unsigned short)src[e];
    }
}

// ---------------------------------------------------------------------------
// XCD-sliced gather with per-block DEGREE SORT: block = (128 nodes, slice of
// 16 cols); slice = blockIdx&7 pins each slice to one XCD L2 (R4-verified).
// New: nodes are counting-ranked by degree in LDS and threads remapped so
// each wave (32 nodes) has near-uniform degree -> edge-loop trip count per
// wave drops from max(deg of 32 random) ~19.6 to ~quartile max ~14.5.
// 2 lanes/node, 16B loads, 8-deep unroll. MEAN: scale by inv_deg.
// ---------------------------------------------------------------------------
template<bool MEAN>
__global__ __launch_bounds__(256) void gather_slice_kernel(
    const unsigned short* __restrict__ feat_s,
    const int* __restrict__ row_beg, const int* __restrict__ row_end,
    const unsigned short* __restrict__ csr_src,
    const float* __restrict__ inv_deg,
    unsigned short* __restrict__ out_s)
{
    __shared__ unsigned short idxbuf[IDXCAP];
    __shared__ int hist[64];
    __shared__ int hbase[64];
    __shared__ unsigned char perm[128];
    const int t = threadIdx.x;
    const int slice = blockIdx.x & 7;
    const int grp = blockIdx.x >> 3;
    const int node0 = grp * 128;
    const int nlast = (node0 + 127 < N_NODES) ? node0 + 127 : N_NODES - 1;
    const int l8 = (t & 1) * 8;
    const unsigned short* fbase = feat_s + (size_t)slice * SLICE_STRIDE + l8;

    // ---- degree-rank the block's 128 nodes ----
    if (t < 64) hist[t] = 0;
    __syncthreads();
    int myd = 0, myoff = 0;
    if (t < 128) {
        int nd = node0 + t;
        int d = (nd < N_NODES) ? row_end[nd] - row_beg[nd] : 0;
        myd = d > 63 ? 63 : d;
        myoff = atomicAdd(&hist[myd], 1);
    }
    __syncthreads();
    if (t < 64) {
        int v = hist[t];
#pragma unroll
        for (int off = 1; off < 64; off <<= 1) {
            int u = __shfl_up(v, off, 64);
            if (t >= off) v += u;
        }
        hbase[t] = v - hist[t];   // exclusive prefix
    }
    __syncthreads();
    if (t < 128) perm[hbase[myd] + myoff] = (unsigned char)t;

    // ---- stage the block's contiguous CSR index range ----
    const int ebeg = row_beg[node0];
    const int ecnt = row_end[nlast] - ebeg;
    const bool lds_ok = (ecnt <= IDXCAP);
    if (lds_ok)
        for (int i = t; i < ecnt; i += 256) idxbuf[i] = csr_src[ebeg + i];
    __syncthreads();   // perm + idxbuf ready

    const int node = node0 + perm[t >> 1];
    if (node >= N_NODES) return;

    const int beg = row_beg[node];
    const int deg = row_end[node] - beg;

    float a[8];
#pragma unroll
    for (int j = 0; j < 8; j++) a[j] = 0.f;

    if (lds_ok) {
        const int off = beg - ebeg;
        int e = 0;
        for (; e + 7 < deg; e += 8) {
            int s[8];
#pragma unroll
            for (int u = 0; u < 8; u++) s[u] = idxbuf[off + e + u];
            bf16x8 v[8];
#pragma unroll
            for (int u = 0; u < 8; u++)
                v[u] = *(const bf16x8*)(fbase + (size_t)s[u] * 16);
#pragma unroll
            for (int u = 0; u < 8; u++)
#pragma unroll
                for (int j = 0; j < 8; j++)
                    a[j] += b2f((unsigned short)v[u][j]);
        }
        for (; e + 3 < deg; e += 4) {
            int s[4];
#pragma unroll
            for (int u = 0; u < 4; u++) s[u] = idxbuf[off + e + u];
            bf16x8 v[4];
#pragma unroll
            for (int u = 0; u < 4; u++)
                v[u] = *(const bf16x8*)(fbase + (size_t)s[u] * 16);
#pragma unroll
            for (int u = 0; u < 4; u++)
#pragma unroll
                for (int j = 0; j < 8; j++)
                    a[j] += b2f((unsigned short)v[u][j]);
        }
        for (; e < deg; e++) {
            int s0 = idxbuf[off + e];
            bf16x8 v0 = *(const bf16x8*)(fbase + (size_t)s0 * 16);
#pragma unroll
            for (int j = 0; j < 8; j++)
                a[j] += b2f((unsigned short)v0[j]);
        }
    } else {
        // pathological skew fallback
        for (int e = beg; e < beg + deg; e++) {
            int s0 = csr_src[e];
            bf16x8 v0 = *(const bf16x8*)(fbase + (size_t)s0 * 16);
#pragma unroll
            for (int j = 0; j < 8; j++)
                a[j] += b2f((unsigned short)v0[j]);
        }
    }

    if (MEAN) {
        float sc = inv_deg[node];
#pragma unroll
        for (int j = 0; j < 8; j++) a[j] *= sc;
    }
    bf16x8 o;
#pragma unroll
    for (int j = 0; j < 8; j++) o[j] = (short)f2b(a[j]);
    *(bf16x8*)(out_s + (size_t)slice * SLICE_STRIDE + (size_t)node * 16 + l8) = o;
}

// ---------------------------------------------------------------------------
// Fused GIN GEMM (sliced A/C): Cb = bf16( relu((X+AGG)@W1+b1) @ W2 + b2 ).
// Weights register-stationary; T1 via 32x136 LDS tile. Stats 8-replica.
// ---------------------------------------------------------------------------
__global__ __launch_bounds__(256, 2) void gemm_gin_kernel(
    const unsigned short* __restrict__ X, const unsigned short* __restrict__ AGG,
    const unsigned short* __restrict__ W1t, const unsigned short* __restrict__ W2t,
    const float* __restrict__ b1, const float* __restrict__ b2,
    float* __restrict__ stats, unsigned short* __restrict__ Cb,
    int M, int ntiles)
{
    __shared__ unsigned short t1[32][136];
    __shared__ float red[2][128];

    const int t = threadIdx.x;
    const int wave = t >> 6;
    const int lane = t & 63;
    const int colhalf = wave & 1;
    const int rowpair = wave >> 1;
    const int m16 = lane & 15;
    const int quad = lane >> 4;
    const int k0 = quad * 8;
    const int colbase = colhalf * 64;
    const int lrow = rowpair * 16 + m16;

    const bf16x8 zero8 = {0, 0, 0, 0, 0, 0, 0, 0};

    bf16x8 w1f[4][4], w2f[4][4];
#pragma unroll
    for (int ct = 0; ct < 4; ct++) {
        int col = colbase + ct * 16 + m16;
#pragma unroll
        for (int kc = 0; kc < 4; kc++) {
            w1f[ct][kc] = *(const bf16x8*)(W1t + (size_t)col * 128 + kc * 32 + k0);
            w2f[ct][kc] = *(const bf16x8*)(W2t + (size_t)col * 128 + kc * 32 + k0);
        }
    }
    f32x4 bs1[4], bs2[4];
#pragma unroll
    for (int ct = 0; ct < 4; ct++) {
        bs1[ct] = *(const f32x4*)(b1 + colbase + ct * 16 + quad * 4);
        bs2[ct] = *(const f32x4*)(b2 + colbase + ct * 16 + quad * 4);
    }

    float psum[4][4], psq[4][4];
#pragma unroll
    for (int ct = 0; ct < 4; ct++)
#pragma unroll
        for (int r = 0; r < 4; r++) { psum[ct][r] = 0.f; psq[ct][r] = 0.f; }

    for (int tile = blockIdx.x; tile < ntiles; tile += gridDim.x) {
        int arow = tile * 32 + rowpair * 16 + m16;
        bool aok = arow < M;

        // A = bf16(x + agg); col = kc*32 + quad*8 -> slice = 2*kc + (quad>>1)
        bf16x8 a[4];
#pragma unroll
        for (int kc = 0; kc < 4; kc++) {
            if (aok) {
                size_t aoff = (size_t)(kc * 2 + (quad >> 1)) * SLICE_STRIDE
                            + (size_t)arow * 16 + (quad & 1) * 8;
                bf16x8 vx = *(const bf16x8*)(X + aoff);
                bf16x8 vg = *(const bf16x8*)(AGG + aoff);
                bf16x8 r;
#pragma unroll
                for (int i = 0; i < 8; i++)
                    r[i] = (short)f2b(b2f((unsigned short)vx[i]) + b2f((unsigned short)vg[i]));
                a[kc] = r;
            } else {
                a[kc] = zero8;
            }
        }

        // phase 1
        f32x4 acc[4];
#pragma unroll
        for (int ct = 0; ct < 4; ct++) acc[ct] = (f32x4){0.f, 0.f, 0.f, 0.f};
#pragma unroll
        for (int kc = 0; kc < 4; kc++)
#pragma unroll
            for (int ct = 0; ct < 4; ct++)
                acc[ct] = __builtin_amdgcn_mfma_f32_16x16x32_bf16(w1f[ct][kc], a[kc], acc[ct], 0, 0, 0);

        __syncthreads();   // previous tile's t1 reads done
#pragma unroll
        for (int ct = 0; ct < 4; ct++) {
            f32x4 v = acc[ct] + bs1[ct];
            ushort4 o;
            o.x = f2b(fmaxf(v[0], 0.f));
            o.y = f2b(fmaxf(v[1], 0.f));
            o.z = f2b(fmaxf(v[2], 0.f));
            o.w = f2b(fmaxf(v[3], 0.f));
            *(ushort4*)&t1[lrow][colbase + ct * 16 + quad * 4] = o;
        }
        __syncthreads();

        // phase 2
        bf16x8 ta[4];
#pragma unroll
        for (int kc = 0; kc < 4; kc++)
            ta[kc] = *(const bf16x8*)&t1[lrow][kc * 32 + k0];

        f32x4 acc2[4];
#pragma unroll
        for (int ct = 0; ct < 4; ct++) acc2[ct] = (f32x4){0.f, 0.f, 0.f, 0.f};
#pragma unroll
        for (int kc = 0; kc < 4; kc++)
#pragma unroll
            for (int ct = 0; ct < 4; ct++)
                acc2[ct] = __builtin_amdgcn_mfma_f32_16x16x32_bf16(w2f[ct][kc], ta[kc], acc2[ct], 0, 0, 0);

        if (arow < M) {
#pragma unroll
            for (int ct = 0; ct < 4; ct++) {
                f32x4 v = acc2[ct] + bs2[ct];
#pragma unroll
                for (int r = 0; r < 4; r++) { psum[ct][r] += v[r]; psq[ct][r] += v[r] * v[r]; }
                ushort4 o;
                o.x = f2b(v[0]); o.y = f2b(v[1]); o.z = f2b(v[2]); o.w = f2b(v[3]);
                int cs = (colbase >> 4) + ct;
                *(ushort4*)(Cb + (size_t)cs * SLICE_STRIDE + (size_t)arow * 16 + quad * 4) = o;
            }
        }
    }

    // stats flush (8-replica)
#pragma unroll
    for (int ct = 0; ct < 4; ct++)
#pragma unroll
        for (int r = 0; r < 4; r++) {
#pragma unroll
            for (int mask = 1; mask <= 8; mask <<= 1) {
                psum[ct][r] += __shfl_xor(psum[ct][r], mask, 64);
                psq[ct][r]  += __shfl_xor(psq[ct][r], mask, 64);
            }
        }
    __syncthreads();
    if (m16 == 0) {
#pragma unroll
        for (int ct = 0; ct < 4; ct++)
#pragma unroll
            for (int r = 0; r < 4; r++)
                red[rowpair][colbase + ct * 16 + quad * 4 + r] = psum[ct][r];
    }
    __syncthreads();
    if (t < 128) atomicAdd(&stats[(blockIdx.x & 7) * 256 + t], red[0][t] + red[1][t]);
    __syncthreads();
    if (m16 == 0) {
#pragma unroll
        for (int ct = 0; ct < 4; ct++)
#pragma unroll
            for (int r = 0; r < 4; r++)
                red[rowpair][colbase + ct * 16 + quad * 4 + r] = psq[ct][r];
    }
    __syncthreads();
    if (t < 128) atomicAdd(&stats[(blockIdx.x & 7) * 256 + 128 + t], red[0][t] + red[1][t]);
}

// ---------------------------------------------------------------------------
// Dual-matrix GEMM (SAGE, sliced A/C): Cb = bf16(A1@W1 + A2@W2 + bias).
// ---------------------------------------------------------------------------
__global__ __launch_bounds__(256) void gemm_dual_kernel(
    const unsigned short* __restrict__ A1, const unsigned short* __restrict__ A2,
    const unsigned short* __restrict__ W1t, const unsigned short* __restrict__ W2t,
    const float* __restrict__ bias, float* __restrict__ stats,
    unsigned short* __restrict__ Cb, int M, int ntiles)
{
    __shared__ float red[128];

    const int t = threadIdx.x;
    const int wave = t >> 6;
    const int lane = t & 63;
    const int m16 = lane & 15;
    const int quad = lane >> 4;
    const int k0 = quad * 8;
    const int colbase = wave * 32;

    const bf16x8 zero8 = {0, 0, 0, 0, 0, 0, 0, 0};

    bf16x8 w1f[2][4], w2f[2][4];
#pragma unroll
    for (int ct = 0; ct < 2; ct++) {
        int col = colbase + ct * 16 + m16;
#pragma unroll
        for (int kc = 0; kc < 4; kc++) {
            w1f[ct][kc] = *(const bf16x8*)(W1t + (size_t)col * 128 + kc * 32 + k0);
            w2f[ct][kc] = *(const bf16x8*)(W2t + (size_t)col * 128 + kc * 32 + k0);
        }
    }
    f32x4 bs[2];
#pragma unroll
    for (int ct = 0; ct < 2; ct++)
        bs[ct] = *(const f32x4*)(bias + colbase + ct * 16 + quad * 4);

    float psum[2][4], psq[2][4];
#pragma unroll
    for (int ct = 0; ct < 2; ct++)
#pragma unroll
        for (int r = 0; r < 4; r++) { psum[ct][r] = 0.f; psq[ct][r] = 0.f; }

    bf16x8 a1[4], a2[4], a1n[4], a2n[4];

    int tile = blockIdx.x;
    if (tile < ntiles) {
        int arow = tile * 16 + m16;
        bool aok = arow < M;
#pragma unroll
        for (int kc = 0; kc < 4; kc++) {
            size_t aoff = (size_t)(kc * 2 + (quad >> 1)) * SLICE_STRIDE
                        + (size_t)arow * 16 + (quad & 1) * 8;
            a1[kc] = aok ? *(const bf16x8*)(A1 + aoff) : zero8;
            a2[kc] = aok ? *(const bf16x8*)(A2 + aoff) : zero8;
        }
    }

    for (; tile < ntiles; tile += gridDim.x) {
        int nt = tile + gridDim.x;
        if (nt < ntiles) {
            int arow = nt * 16 + m16;
            bool aok = arow < M;
#pragma unroll
            for (int kc = 0; kc < 4; kc++) {
                size_t aoff = (size_t)(kc * 2 + (quad >> 1)) * SLICE_STRIDE
                            + (size_t)arow * 16 + (quad & 1) * 8;
                a1n[kc] = aok ? *(const bf16x8*)(A1 + aoff) : zero8;
                a2n[kc] = aok ? *(const bf16x8*)(A2 + aoff) : zero8;
            }
        }

        f32x4 acc[2];
        acc[0] = (f32x4){0.f, 0.f, 0.f, 0.f};
        acc[1] = (f32x4){0.f, 0.f, 0.f, 0.f};
#pragma unroll
        for (int kc = 0; kc < 4; kc++) {
#pragma unroll
            for (int ct = 0; ct < 2; ct++) {
                acc[ct] = __builtin_amdgcn_mfma_f32_16x16x32_bf16(w1f[ct][kc], a1[kc], acc[ct], 0, 0, 0);
                acc[ct] = __builtin_amdgcn_mfma_f32_16x16x32_bf16(w2f[ct][kc], a2[kc], acc[ct], 0, 0, 0);
            }
        }

        int orow = tile * 16 + m16;
        if (orow < M) {
#pragma unroll
            for (int ct = 0; ct < 2; ct++) {
                f32x4 v = acc[ct] + bs[ct];
#pragma unroll
                for (int r = 0; r < 4; r++) { psum[ct][r] += v[r]; psq[ct][r] += v[r] * v[r]; }
                ushort4 o;
                o.x = f2b(v[0]); o.y = f2b(v[1]); o.z = f2b(v[2]); o.w = f2b(v[3]);
                int cs = wave * 2 + ct;
                *(ushort4*)(Cb + (size_t)cs * SLICE_STRIDE + (size_t)orow * 16 + quad * 4) = o;
            }
        }

        if (nt < ntiles) {
            a1[0] = a1n[0]; a1[1] = a1n[1]; a1[2] = a1n[2]; a1[3] = a1n[3];
            a2[0] = a2n[0]; a2[1] = a2n[1]; a2[2] = a2n[2]; a2[3] = a2n[3];
        }
    }

#pragma unroll
    for (int ct = 0; ct < 2; ct++)
#pragma unroll
        for (int r = 0; r < 4; r++) {
#pragma unroll
            for (int mask = 1; mask <= 8; mask <<= 1) {
                psum[ct][r] += __shfl_xor(psum[ct][r], mask, 64);
                psq[ct][r]  += __shfl_xor(psq[ct][r], mask, 64);
            }
        }
    if (m16 == 0) {
#pragma unroll
        for (int ct = 0; ct < 2; ct++)
#pragma unroll
            for (int r = 0; r < 4; r++)
                red[colbase + ct * 16 + quad * 4 + r] = psum[ct][r];
    }
    __syncthreads();
    if (t < 128) atomicAdd(&stats[(blockIdx.x & 7) * 256 + t], red[t]);
    __syncthreads();
    if (m16 == 0) {
#pragma unroll
        for (int ct = 0; ct < 2; ct++)
#pragma unroll
            for (int r = 0; r < 4; r++)
                red[colbase + ct * 16 + quad * 4 + r] = psq[ct][r];
    }
    __syncthreads();
    if (t < 128) atomicAdd(&stats[(blockIdx.x & 7) * 256 + 128 + t], red[t]);
}

// ---------------------------------------------------------------------------
// finish: Hact = relu(bn(Hpre)); sliced layout, linear 16B/thread streaming
// ---------------------------------------------------------------------------
__global__ __launch_bounds__(256) void finish_kernel(
    const unsigned short* __restrict__ Hpre, const float* __restrict__ stats,
    const float* __restrict__ gamma, const float* __restrict__ beta,
    unsigned short* __restrict__ Hact)
{
    __shared__ float cs[2][128];
    int t = threadIdx.x;
    if (t < 128) {
        float mu = stats_sum(stats, t) * INV_N;
        float var = stats_sum(stats, 128 + t) * INV_N - mu * mu;
        float rs = rsqrtf(var + BN_EPS);
        float c = gamma[t] * rs;
        cs[0][t] = c;
        cs[1][t] = beta[t] - mu * c;
    }
    __syncthreads();
    int gid = blockIdx.x * 256 + t;          // 800000 chunks of 8 elems
    int e0 = gid * 8;
    int s = (unsigned)e0 / SLICE_STRIDE;
    int rem = e0 - s * SLICE_STRIDE;
    int col0 = s * 16 + (rem & 15);
    bf16x8 v = *(const bf16x8*)(Hpre + e0);
    bf16x8 o;
#pragma unroll
    for (int j = 0; j < 8; j++)
        o[j] = (short)f2b(fmaxf(b2f((unsigned short)v[j]) * cs[0][col0 + j] + cs[1][col0 + j], 0.f));
    *(bf16x8*)(Hact + e0) = o;
}

// ---------------------------------------------------------------------------
// global mean pool (sliced input): BN affine from stats, relu, mean.
// 256 thr: 16 row-groups x 16 col-chunks (16B/lane).
// ---------------------------------------------------------------------------
__global__ __launch_bounds__(256) void pool_mean_kernel(const unsigned short* __restrict__ h_s,
                                                        const int* __restrict__ gstart,
                                                        const float* __restrict__ stats,
                                                        const float* __restrict__ gamma,
                                                        const float* __restrict__ beta,
                                                        float* __restrict__ out) {
    __shared__ float red[16][128];
    int g = blockIdx.x;
    int t = threadIdx.x;
    int grp = t >> 4;
    int ci = t & 15;
    int c0 = ci * 8;
    float c[8], b[8];
#pragma unroll
    for (int j = 0; j < 8; j++) {
        int col = c0 + j;
        float mu = stats_sum(stats, col) * INV_N;
        float var = stats_sum(stats, 128 + col) * INV_N - mu * mu;
        float rs = rsqrtf(var + BN_EPS);
        c[j] = gamma[col] * rs;
        b[j] = beta[col] - mu * c[j];
    }
    int beg = gstart[g];
    int end = gstart[g + 1];
    float sa[8];
#pragma unroll
    for (int j = 0; j < 8; j++) sa[j] = 0.f;
    // slice = c0>>4 = ci>>1, off = (ci&1)*8
    const unsigned short* base = h_s + (size_t)(ci >> 1) * SLICE_STRIDE + (ci & 1) * 8;
    for (int i = beg + grp; i < end; i += 16) {
        bf16x8 v = *(const bf16x8*)(base + (size_t)i * 16);
#pragma unroll
        for (int j = 0; j < 8; j++)
            sa[j] += fmaxf(b2f((unsigned short)v[j]) * c[j] + b[j], 0.f);
    }
#pragma unroll
    for (int j = 0; j < 8; j++) red[grp][c0 + j] = sa[j];
    __syncthreads();
    if (t < 128) {
        float cnt = fmaxf((float)(end - beg), 1.0f);
        float tot = 0.f;
#pragma unroll
        for (int r = 0; r < 16; r++) tot += red[r][t];
        out[(size_t)g * 128 + t] = tot / cnt;
    }
}

// ---------------------------------------------------------------------------
extern "C" void kernel_launch(void* const* d_in, const int* in_sizes, int n_in,
                              void* d_out, int out_size, void* d_ws, size_t ws_size,
                              hipStream_t stream) {
    const float* x    = (const float*)d_in[0];
    const int*   ei   = (const int*)d_in[1];
    const int*   src  = ei;
    const int*   dst  = ei + N_EDGES;
    const int*   batch = (const int*)d_in[2];
    const float* gw1  = (const float*)d_in[3];
    const float* gb1  = (const float*)d_in[4];
    const float* gw2  = (const float*)d_in[5];
    const float* gb2  = (const float*)d_in[6];
    const float* swl  = (const float*)d_in[7];
    const float* sbl  = (const float*)d_in[8];
    const float* swr  = (const float*)d_in[9];
    const float* bng  = (const float*)d_in[10];
    const float* bnb  = (const float*)d_in[11];
    float* out = (float*)d_out;

    // workspace layout (float units; bf16 buffers 16B-aligned)
    float* ws = (float*)d_ws;
    unsigned short* x16_s  = (unsigned short*)(ws + 0);         // sliced [8][50000][16]
    unsigned short* agg_s  = (unsigned short*)(ws + 3200000);
    unsigned short* hact_s = (unsigned short*)(ws + 6400000);
    unsigned short* hpre_s = (unsigned short*)(ws + 9600000);
    unsigned short* wt     = (unsigned short*)(ws + 12800000);  // 6*16384 u16
    float*          inv_deg= ws + 12850000;                     // 50000
    int*            row_beg= (int*)(ws + 12900000);             // 50000
    int*            cursor = (int*)(ws + 12950000);             // 50000 | total | stats(3*8*256)
    int*            total  = cursor + 50000;
    float*          stats  = (float*)(cursor + 50001);          // 3 layers x 8 replicas x 256
    unsigned short* csr_src= (unsigned short*)(ws + 13100000);  // 600000 u16
    int*            gstart = (int*)(ws + 13700000);             // 513

    const int ggrid = 512;
    const int ntiles32 = (N_NODES + 31) / 32;                   // 1563
    const int ntiles16 = (N_NODES + 15) / 16;                   // 3125
    const int gather_grid = GATHER_GROUPS * NSLICES;            // 3128

    // ---- init: cursor + total + stats in one memset ----
    hipMemsetAsync(cursor, 0, (50001 + 3 * 8 * 256) * sizeof(int), stream);

    // ---- prep: x->bf16 sliced, weights->bf16^T, degree count ----
    prep_kernel<<<CONVX_BLOCKS + WCONV_BLOCKS + DEG_BLOCKS, 256, 0, stream>>>(
        x, gw1, gw2, swl, swr, dst, x16_s, wt, cursor);

    // ---- CSR ----
    alloc_kernel<<<ALLOC_BLOCKS + 3, 256, 0, stream>>>(cursor, row_beg, inv_deg, total, batch, gstart);
    csr_fill_kernel<<<(N_EDGES + 255) / 256, 256, 0, stream>>>(src, dst, cursor, csr_src, N_EDGES);

    // ---- GIN ----
    gather_slice_kernel<false><<<gather_grid, 256, 0, stream>>>(
        x16_s, row_beg, cursor, csr_src, nullptr, agg_s);
    gemm_gin_kernel<<<ggrid, 256, 0, stream>>>(
        x16_s, agg_s, wt + 0 * 16384, wt + 1 * 16384, gb1, gb2,
        stats + 0 * 2048, hpre_s, N_NODES, ntiles32);
    finish_kernel<<<3125, 256, 0, stream>>>(
        hpre_s, stats + 0 * 2048, bng + 0 * HID, bnb + 0 * HID, hact_s);

    // ---- SAGE 0 ----
    gather_slice_kernel<true><<<gather_grid, 256, 0, stream>>>(
        hact_s, row_beg, cursor, csr_src, inv_deg, agg_s);
    gemm_dual_kernel<<<ggrid, 256, 0, stream>>>(
        agg_s, hact_s, wt + 2 * 16384, wt + 3 * 16384, sbl + 0 * HID,
        stats + 1 * 2048, hpre_s, N_NODES, ntiles16);
    finish_kernel<<<3125, 256, 0, stream>>>(
        hpre_s, stats + 1 * 2048, bng + 1 * HID, bnb + 1 * HID, hact_s);

    // ---- SAGE 1 ----
    gather_slice_kernel<true><<<gather_grid, 256, 0, stream>>>(
        hact_s, row_beg, cursor, csr_src, inv_deg, agg_s);
    gemm_dual_kernel<<<ggrid, 256, 0, stream>>>(
        agg_s, hact_s, wt + 4 * 16384, wt + 5 * 16384, sbl + 1 * HID,
        stats + 2 * 2048, hpre_s, N_NODES, ntiles16);

    // ---- pool (BN2 affine folded) ----
    pool_mean_kernel<<<N_GRAPHS, 256, 0, stream>>>(
        hpre_s, gstart, stats + 2 * 2048, bng + 2 * HID, bnb + 2 * HID, out);
}

// Round 11
// 295.583 us; speedup vs baseline: 1.1921x; 1.0674x over previous
//
#include <hip/hip_runtime.h>

#define N_NODES 50000
#define N_EDGES 600000
#define HID 128
#define N_GRAPHS 512
#define BN_EPS 1e-5f
#define INV_N (1.0f / 50000.0f)
#define SLICE_STRIDE 1600000    // 50000 * 32 u16 elems per column-slice
#define NSLICES 4
#define GATHER_GROUPS 782       // ceil(50000/64)
#define IDXCAP 2048

typedef __attribute__((ext_vector_type(8))) short bf16x8;
typedef __attribute__((ext_vector_type(4))) float f32x4;

__device__ __forceinline__ unsigned short f2b(float f) {
    unsigned u = __float_as_uint(f);
    return (unsigned short)((u + 0x7FFFu + ((u >> 16) & 1u)) >> 16);
}
__device__ __forceinline__ float b2f(unsigned short h) {
    return __uint_as_float(((unsigned)h) << 16);
}

// sum the 8 stats replicas
__device__ __forceinline__ float stats_sum(const float* __restrict__ s, int idx) {
    float v = 0.f;
#pragma unroll
    for (int r = 0; r < 8; r++) v += s[r * 256 + idx];
    return v;
}

// ---------------------------------------------------------------------------
// prep: x -> bf16 (32-col sliced) | transpose+convert 6 weight mats | degree
// ---------------------------------------------------------------------------
#define CONVX_BLOCKS 6250
#define WCONV_BLOCKS 384
#define DEG_BLOCKS   2344
__global__ __launch_bounds__(256) void prep_kernel(
    const float* __restrict__ x, const float* __restrict__ gw1, const float* __restrict__ gw2,
    const float* __restrict__ swl, const float* __restrict__ swr, const int* __restrict__ dst,
    unsigned short* __restrict__ x16, unsigned short* __restrict__ wt, int* __restrict__ deg)
{
    int b = blockIdx.x;
    int t = threadIdx.x;
    if (b < CONVX_BLOCKS) {
        int gid = b * 256 + t;
        int i = gid >> 5, l = gid & 31;
        if (i >= N_NODES) return;
        int c0 = l * 4;
        float4 v = *(const float4*)(x + (size_t)i * 128 + c0);
        ushort4 o;
        o.x = f2b(v.x); o.y = f2b(v.y); o.z = f2b(v.z); o.w = f2b(v.w);
        // slice = c0>>5 = l>>3 ; off = c0&31 = (l&7)*4
        *(ushort4*)(x16 + (size_t)(l >> 3) * SLICE_STRIDE + (size_t)i * 32 + (l & 7) * 4) = o;
    } else if (b < CONVX_BLOCKS + WCONV_BLOCKS) {
        int gid = (b - CONVX_BLOCKS) * 256 + t;   // < 6*16384
        int m = gid >> 14;
        int e = gid & 16383;
        int k = e >> 7;
        int n = e & 127;
        const float* src = (m == 0) ? gw1 : (m == 1) ? gw2 : (m == 2) ? swl
                         : (m == 3) ? swr : (m == 4) ? (swl + 16384) : (swr + 16384);
        wt[m * 16384 + n * 128 + k] = f2b(src[k * 128 + n]);
    } else {
        int e = (b - CONVX_BLOCKS - WCONV_BLOCKS) * 256 + t;
        if (e < N_EDGES) atomicAdd(&deg[dst[e]], 1);
    }
}

// ---------------------------------------------------------------------------
// alloc (per-block scan + atomic base) + gstart (binary search), fused
// ---------------------------------------------------------------------------
#define ALLOC_BLOCKS 196
__global__ __launch_bounds__(256) void alloc_kernel(int* __restrict__ cursor,
                                                    int* __restrict__ row_beg,
                                                    float* __restrict__ inv_deg,
                                                    int* __restrict__ total,
                                                    const int* __restrict__ batch,
                                                    int* __restrict__ gstart) {
    if (blockIdx.x >= ALLOC_BLOCKS) {
        int g = (blockIdx.x - ALLOC_BLOCKS) * 256 + threadIdx.x;
        if (g > N_GRAPHS) return;
        int lo = 0, hi = N_NODES;
        while (lo < hi) {
            int mid = (lo + hi) >> 1;
            if (batch[mid] < g) lo = mid + 1; else hi = mid;
        }
        gstart[g] = lo;
        return;
    }
    __shared__ int tmp[256];
    __shared__ int base;
    int i = blockIdx.x * 256 + threadIdx.x;
    int d = (i < N_NODES) ? cursor[i] : 0;
    tmp[threadIdx.x] = d;
    __syncthreads();
#pragma unroll
    for (int off = 1; off < 256; off <<= 1) {
        int v = (threadIdx.x >= off) ? tmp[threadIdx.x - off] : 0;
        __syncthreads();
        tmp[threadIdx.x] += v;
        __syncthreads();
    }
    if (threadIdx.x == 255) base = atomicAdd(total, tmp[255]);
    __syncthreads();
    if (i < N_NODES) {
        int b = base + tmp[threadIdx.x] - d;
        row_beg[i] = b;
        cursor[i] = b;
        inv_deg[i] = 1.0f / fmaxf((float)d, 1.0f);
    }
}

__global__ void csr_fill_kernel(const int* __restrict__ src, const int* __restrict__ dst,
                                int* __restrict__ cursor, unsigned short* __restrict__ csr_src, int nE) {
    int e = blockIdx.x * blockDim.x + threadIdx.x;
    if (e < nE) {
        int pos = atomicAdd(&cursor[dst[e]], 1);
        csr_src[pos] = (unsigned short)src[e];
    }
}

// ---------------------------------------------------------------------------
// XCD-sliced gather, 32-col slices: block = (64 nodes, slice of 32 cols).
// slice = blockIdx & 3 -> each slice resident in 2 XCD L2s (3.2 MB table).
// 4 lanes/node read one contiguous 64-B row per edge => HALF the L2 requests
// of the 16-col layout (request-rate-bound regime). agg stores are
// NON-TEMPORAL (write-once; GEMM re-reads from HBM ~6 us) so the table is
// the only resident stream. idx loads stay cached (8x reuse across slices).
// 8-deep unroll. MEAN: scale by inv_deg.
// ---------------------------------------------------------------------------
template<bool MEAN>
__global__ __launch_bounds__(256) void gather_slice_kernel(
    const unsigned short* __restrict__ feat_s,
    const int* __restrict__ row_beg, const int* __restrict__ row_end,
    const unsigned short* __restrict__ csr_src,
    const float* __restrict__ inv_deg,
    unsigned short* __restrict__ out_s)
{
    __shared__ unsigned short idxbuf[IDXCAP];
    const int t = threadIdx.x;
    const int slice = blockIdx.x & 3;
    const int grp = blockIdx.x >> 2;
    const int node0 = grp * 64;
    const int nlast = (node0 + 63 < N_NODES) ? node0 + 63 : N_NODES - 1;
    const int node = node0 + (t >> 2);
    const int l8 = (t & 3) * 8;
    const unsigned short* fbase = feat_s + (size_t)slice * SLICE_STRIDE + l8;

    const int ebeg = row_beg[node0];
    const int ecnt = row_end[nlast] - ebeg;
    const bool lds_ok = (ecnt <= IDXCAP);
    if (lds_ok)
        for (int i = t; i < ecnt; i += 256) idxbuf[i] = csr_src[ebeg + i];
    __syncthreads();
    if (node >= N_NODES) return;

    const int beg = row_beg[node];
    const int deg = row_end[node] - beg;

    float a[8];
#pragma unroll
    for (int j = 0; j < 8; j++) a[j] = 0.f;

    if (lds_ok) {
        const int off = beg - ebeg;
        int e = 0;
        for (; e + 7 < deg; e += 8) {
            int s[8];
#pragma unroll
            for (int u = 0; u < 8; u++) s[u] = idxbuf[off + e + u];
            bf16x8 v[8];
#pragma unroll
            for (int u = 0; u < 8; u++)
                v[u] = *(const bf16x8*)(fbase + (size_t)s[u] * 32);
#pragma unroll
            for (int u = 0; u < 8; u++)
#pragma unroll
                for (int j = 0; j < 8; j++)
                    a[j] += b2f((unsigned short)v[u][j]);
        }
        for (; e + 3 < deg; e += 4) {
            int s[4];
#pragma unroll
            for (int u = 0; u < 4; u++) s[u] = idxbuf[off + e + u];
            bf16x8 v[4];
#pragma unroll
            for (int u = 0; u < 4; u++)
                v[u] = *(const bf16x8*)(fbase + (size_t)s[u] * 32);
#pragma unroll
            for (int u = 0; u < 4; u++)
#pragma unroll
                for (int j = 0; j < 8; j++)
                    a[j] += b2f((unsigned short)v[u][j]);
        }
        for (; e < deg; e++) {
            int s0 = idxbuf[off + e];
            bf16x8 v0 = *(const bf16x8*)(fbase + (size_t)s0 * 32);
#pragma unroll
            for (int j = 0; j < 8; j++)
                a[j] += b2f((unsigned short)v0[j]);
        }
    } else {
        // pathological skew fallback
        for (int e = beg; e < beg + deg; e++) {
            int s0 = csr_src[e];
            bf16x8 v0 = *(const bf16x8*)(fbase + (size_t)s0 * 32);
#pragma unroll
            for (int j = 0; j < 8; j++)
                a[j] += b2f((unsigned short)v0[j]);
        }
    }

    if (MEAN) {
        float sc = inv_deg[node];
#pragma unroll
        for (int j = 0; j < 8; j++) a[j] *= sc;
    }
    bf16x8 o;
#pragma unroll
    for (int j = 0; j < 8; j++) o[j] = (short)f2b(a[j]);
    __builtin_nontemporal_store(o,
        (bf16x8*)(out_s + (size_t)slice * SLICE_STRIDE + (size_t)node * 32 + l8));
}

// ---------------------------------------------------------------------------
// Fused GIN GEMM (32-col sliced A/C): Cb = bf16( relu((X+AGG)@W1+b1)@W2+b2 ).
// Weights register-stationary; T1 via 32x136 LDS tile. Stats 8-replica.
// (Addressing identical to R5's correctness-verified version.)
// ---------------------------------------------------------------------------
__global__ __launch_bounds__(256, 2) void gemm_gin_kernel(
    const unsigned short* __restrict__ X, const unsigned short* __restrict__ AGG,
    const unsigned short* __restrict__ W1t, const unsigned short* __restrict__ W2t,
    const float* __restrict__ b1, const float* __restrict__ b2,
    float* __restrict__ stats, unsigned short* __restrict__ Cb,
    int M, int ntiles)
{
    __shared__ unsigned short t1[32][136];
    __shared__ float red[2][128];

    const int t = threadIdx.x;
    const int wave = t >> 6;
    const int lane = t & 63;
    const int colhalf = wave & 1;
    const int rowpair = wave >> 1;
    const int m16 = lane & 15;
    const int quad = lane >> 4;
    const int k0 = quad * 8;
    const int colbase = colhalf * 64;
    const int lrow = rowpair * 16 + m16;

    const bf16x8 zero8 = {0, 0, 0, 0, 0, 0, 0, 0};

    bf16x8 w1f[4][4], w2f[4][4];
#pragma unroll
    for (int ct = 0; ct < 4; ct++) {
        int col = colbase + ct * 16 + m16;
#pragma unroll
        for (int kc = 0; kc < 4; kc++) {
            w1f[ct][kc] = *(const bf16x8*)(W1t + (size_t)col * 128 + kc * 32 + k0);
            w2f[ct][kc] = *(const bf16x8*)(W2t + (size_t)col * 128 + kc * 32 + k0);
        }
    }
    f32x4 bs1[4], bs2[4];
#pragma unroll
    for (int ct = 0; ct < 4; ct++) {
        bs1[ct] = *(const f32x4*)(b1 + colbase + ct * 16 + quad * 4);
        bs2[ct] = *(const f32x4*)(b2 + colbase + ct * 16 + quad * 4);
    }

    float psum[4][4], psq[4][4];
#pragma unroll
    for (int ct = 0; ct < 4; ct++)
#pragma unroll
        for (int r = 0; r < 4; r++) { psum[ct][r] = 0.f; psq[ct][r] = 0.f; }

    for (int tile = blockIdx.x; tile < ntiles; tile += gridDim.x) {
        int arow = tile * 32 + rowpair * 16 + m16;
        bool aok = arow < M;

        // A = bf16(x + agg); col k = kc*32 + quad*8 -> slice = kc, off = quad*8
        bf16x8 a[4];
#pragma unroll
        for (int kc = 0; kc < 4; kc++) {
            if (aok) {
                size_t aoff = (size_t)kc * SLICE_STRIDE + (size_t)arow * 32 + quad * 8;
                bf16x8 vx = *(const bf16x8*)(X + aoff);
                bf16x8 vg = *(const bf16x8*)(AGG + aoff);
                bf16x8 r;
#pragma unroll
                for (int i = 0; i < 8; i++)
                    r[i] = (short)f2b(b2f((unsigned short)vx[i]) + b2f((unsigned short)vg[i]));
                a[kc] = r;
            } else {
                a[kc] = zero8;
            }
        }

        // phase 1
        f32x4 acc[4];
#pragma unroll
        for (int ct = 0; ct < 4; ct++) acc[ct] = (f32x4){0.f, 0.f, 0.f, 0.f};
#pragma unroll
        for (int kc = 0; kc < 4; kc++)
#pragma unroll
            for (int ct = 0; ct < 4; ct++)
                acc[ct] = __builtin_amdgcn_mfma_f32_16x16x32_bf16(w1f[ct][kc], a[kc], acc[ct], 0, 0, 0);

        __syncthreads();   // previous tile's t1 reads done
#pragma unroll
        for (int ct = 0; ct < 4; ct++) {
            f32x4 v = acc[ct] + bs1[ct];
            ushort4 o;
            o.x = f2b(fmaxf(v[0], 0.f));
            o.y = f2b(fmaxf(v[1], 0.f));
            o.z = f2b(fmaxf(v[2], 0.f));
            o.w = f2b(fmaxf(v[3], 0.f));
            *(ushort4*)&t1[lrow][colbase + ct * 16 + quad * 4] = o;
        }
        __syncthreads();

        // phase 2
        bf16x8 ta[4];
#pragma unroll
        for (int kc = 0; kc < 4; kc++)
            ta[kc] = *(const bf16x8*)&t1[lrow][kc * 32 + k0];

        f32x4 acc2[4];
#pragma unroll
        for (int ct = 0; ct < 4; ct++) acc2[ct] = (f32x4){0.f, 0.f, 0.f, 0.f};
#pragma unroll
        for (int kc = 0; kc < 4; kc++)
#pragma unroll
            for (int ct = 0; ct < 4; ct++)
                acc2[ct] = __builtin_amdgcn_mfma_f32_16x16x32_bf16(w2f[ct][kc], ta[kc], acc2[ct], 0, 0, 0);

        if (arow < M) {
#pragma unroll
            for (int ct = 0; ct < 4; ct++) {
                f32x4 v = acc2[ct] + bs2[ct];
#pragma unroll
                for (int r = 0; r < 4; r++) { psum[ct][r] += v[r]; psq[ct][r] += v[r] * v[r]; }
                ushort4 o;
                o.x = f2b(v[0]); o.y = f2b(v[1]); o.z = f2b(v[2]); o.w = f2b(v[3]);
                int cloc = ct * 16 + quad * 4;
                int cs = colhalf * 2 + (cloc >> 5);
                int coff = cloc & 31;
                *(ushort4*)(Cb + (size_t)cs * SLICE_STRIDE + (size_t)arow * 32 + coff) = o;
            }
        }
    }

    // stats flush (8-replica)
#pragma unroll
    for (int ct = 0; ct < 4; ct++)
#pragma unroll
        for (int r = 0; r < 4; r++) {
#pragma unroll
            for (int mask = 1; mask <= 8; mask <<= 1) {
                psum[ct][r] += __shfl_xor(psum[ct][r], mask, 64);
                psq[ct][r]  += __shfl_xor(psq[ct][r], mask, 64);
            }
        }
    __syncthreads();
    if (m16 == 0) {
#pragma unroll
        for (int ct = 0; ct < 4; ct++)
#pragma unroll
            for (int r = 0; r < 4; r++)
                red[rowpair][colbase + ct * 16 + quad * 4 + r] = psum[ct][r];
    }
    __syncthreads();
    if (t < 128) atomicAdd(&stats[(blockIdx.x & 7) * 256 + t], red[0][t] + red[1][t]);
    __syncthreads();
    if (m16 == 0) {
#pragma unroll
        for (int ct = 0; ct < 4; ct++)
#pragma unroll
            for (int r = 0; r < 4; r++)
                red[rowpair][colbase + ct * 16 + quad * 4 + r] = psq[ct][r];
    }
    __syncthreads();
    if (t < 128) atomicAdd(&stats[(blockIdx.x & 7) * 256 + 128 + t], red[0][t] + red[1][t]);
}

// ---------------------------------------------------------------------------
// Dual-matrix GEMM (SAGE, 32-col sliced A/C): Cb = bf16(A1@W1 + A2@W2 + b).
// (Addressing identical to R5's correctness-verified version.)
// ---------------------------------------------------------------------------
__global__ __launch_bounds__(256) void gemm_dual_kernel(
    const unsigned short* __restrict__ A1, const unsigned short* __restrict__ A2,
    const unsigned short* __restrict__ W1t, const unsigned short* __restrict__ W2t,
    const float* __restrict__ bias, float* __restrict__ stats,
    unsigned short* __restrict__ Cb, int M, int ntiles)
{
    __shared__ float red[128];

    const int t = threadIdx.x;
    const int wave = t >> 6;
    const int lane = t & 63;
    const int m16 = lane & 15;
    const int quad = lane >> 4;
    const int k0 = quad * 8;
    const int colbase = wave * 32;

    const bf16x8 zero8 = {0, 0, 0, 0, 0, 0, 0, 0};

    bf16x8 w1f[2][4], w2f[2][4];
#pragma unroll
    for (int ct = 0; ct < 2; ct++) {
        int col = colbase + ct * 16 + m16;
#pragma unroll
        for (int kc = 0; kc < 4; kc++) {
            w1f[ct][kc] = *(const bf16x8*)(W1t + (size_t)col * 128 + kc * 32 + k0);
            w2f[ct][kc] = *(const bf16x8*)(W2t + (size_t)col * 128 + kc * 32 + k0);
        }
    }
    f32x4 bs[2];
#pragma unroll
    for (int ct = 0; ct < 2; ct++)
        bs[ct] = *(const f32x4*)(bias + colbase + ct * 16 + quad * 4);

    float psum[2][4], psq[2][4];
#pragma unroll
    for (int ct = 0; ct < 2; ct++)
#pragma unroll
        for (int r = 0; r < 4; r++) { psum[ct][r] = 0.f; psq[ct][r] = 0.f; }

    bf16x8 a1[4], a2[4], a1n[4], a2n[4];

    int tile = blockIdx.x;
    if (tile < ntiles) {
        int arow = tile * 16 + m16;
        bool aok = arow < M;
#pragma unroll
        for (int kc = 0; kc < 4; kc++) {
            size_t aoff = (size_t)kc * SLICE_STRIDE + (size_t)arow * 32 + quad * 8;
            a1[kc] = aok ? *(const bf16x8*)(A1 + aoff) : zero8;
            a2[kc] = aok ? *(const bf16x8*)(A2 + aoff) : zero8;
        }
    }

    for (; tile < ntiles; tile += gridDim.x) {
        int nt = tile + gridDim.x;
        if (nt < ntiles) {
            int arow = nt * 16 + m16;
            bool aok = arow < M;
#pragma unroll
            for (int kc = 0; kc < 4; kc++) {
                size_t aoff = (size_t)kc * SLICE_STRIDE + (size_t)arow * 32 + quad * 8;
                a1n[kc] = aok ? *(const bf16x8*)(A1 + aoff) : zero8;
                a2n[kc] = aok ? *(const bf16x8*)(A2 + aoff) : zero8;
            }
        }

        f32x4 acc[2];
        acc[0] = (f32x4){0.f, 0.f, 0.f, 0.f};
        acc[1] = (f32x4){0.f, 0.f, 0.f, 0.f};
#pragma unroll
        for (int kc = 0; kc < 4; kc++) {
#pragma unroll
            for (int ct = 0; ct < 2; ct++) {
                acc[ct] = __builtin_amdgcn_mfma_f32_16x16x32_bf16(w1f[ct][kc], a1[kc], acc[ct], 0, 0, 0);
                acc[ct] = __builtin_amdgcn_mfma_f32_16x16x32_bf16(w2f[ct][kc], a2[kc], acc[ct], 0, 0, 0);
            }
        }

        int orow = tile * 16 + m16;
        if (orow < M) {
#pragma unroll
            for (int ct = 0; ct < 2; ct++) {
                f32x4 v = acc[ct] + bs[ct];
#pragma unroll
                for (int r = 0; r < 4; r++) { psum[ct][r] += v[r]; psq[ct][r] += v[r] * v[r]; }
                ushort4 o;
                o.x = f2b(v[0]); o.y = f2b(v[1]); o.z = f2b(v[2]); o.w = f2b(v[3]);
                *(ushort4*)(Cb + (size_t)wave * SLICE_STRIDE + (size_t)orow * 32 + ct * 16 + quad * 4) = o;
            }
        }

        if (nt < ntiles) {
            a1[0] = a1n[0]; a1[1] = a1n[1]; a1[2] = a1n[2]; a1[3] = a1n[3];
            a2[0] = a2n[0]; a2[1] = a2n[1]; a2[2] = a2n[2]; a2[3] = a2n[3];
        }
    }

#pragma unroll
    for (int ct = 0; ct < 2; ct++)
#pragma unroll
        for (int r = 0; r < 4; r++) {
#pragma unroll
            for (int mask = 1; mask <= 8; mask <<= 1) {
                psum[ct][r] += __shfl_xor(psum[ct][r], mask, 64);
                psq[ct][r]  += __shfl_xor(psq[ct][r], mask, 64);
            }
        }
    if (m16 == 0) {
#pragma unroll
        for (int ct = 0; ct < 2; ct++)
#pragma unroll
            for (int r = 0; r < 4; r++)
                red[colbase + ct * 16 + quad * 4 + r] = psum[ct][r];
    }
    __syncthreads();
    if (t < 128) atomicAdd(&stats[(blockIdx.x & 7) * 256 + t], red[t]);
    __syncthreads();
    if (m16 == 0) {
#pragma unroll
        for (int ct = 0; ct < 2; ct++)
#pragma unroll
            for (int r = 0; r < 4; r++)
                red[colbase + ct * 16 + quad * 4 + r] = psq[ct][r];
    }
    __syncthreads();
    if (t < 128) atomicAdd(&stats[(blockIdx.x & 7) * 256 + 128 + t], red[t]);
}

// ---------------------------------------------------------------------------
// finish: Hact = relu(bn(Hpre)); 32-col sliced, linear 16B/thread streaming
// ---------------------------------------------------------------------------
__global__ __launch_bounds__(256) void finish_kernel(
    const unsigned short* __restrict__ Hpre, const float* __restrict__ stats,
    const float* __restrict__ gamma, const float* __restrict__ beta,
    unsigned short* __restrict__ Hact)
{
    __shared__ float cs[2][128];
    int t = threadIdx.x;
    if (t < 128) {
        float mu = stats_sum(stats, t) * INV_N;
        float var = stats_sum(stats, 128 + t) * INV_N - mu * mu;
        float rs = rsqrtf(var + BN_EPS);
        float c = gamma[t] * rs;
        cs[0][t] = c;
        cs[1][t] = beta[t] - mu * c;
    }
    __syncthreads();
    int gid = blockIdx.x * 256 + t;          // 800000 chunks of 8 elems
    size_t e0 = (size_t)gid * 8;
    int s = (int)(e0 / SLICE_STRIDE);
    int col0 = s * 32 + (int)(e0 & 31);      // SLICE_STRIDE % 32 == 0
    bf16x8 v = *(const bf16x8*)(Hpre + e0);
    bf16x8 o;
#pragma unroll
    for (int j = 0; j < 8; j++)
        o[j] = (short)f2b(fmaxf(b2f((unsigned short)v[j]) * cs[0][col0 + j] + cs[1][col0 + j], 0.f));
    *(bf16x8*)(Hact + e0) = o;
}

// ---------------------------------------------------------------------------
// global mean pool (32-col sliced input): BN affine from stats, relu, mean.
// 256 thr: 16 row-groups x 16 col-chunks (16B/lane).
// ---------------------------------------------------------------------------
__global__ __launch_bounds__(256) void pool_mean_kernel(const unsigned short* __restrict__ h_s,
                                                        const int* __restrict__ gstart,
                                                        const float* __restrict__ stats,
                                                        const float* __restrict__ gamma,
                                                        const float* __restrict__ beta,
                                                        float* __restrict__ out) {
    __shared__ float red[16][128];
    int g = blockIdx.x;
    int t = threadIdx.x;
    int grp = t >> 4;
    int ci = t & 15;
    int c0 = ci * 8;
    float c[8], b[8];
#pragma unroll
    for (int j = 0; j < 8; j++) {
        int col = c0 + j;
        float mu = stats_sum(stats, col) * INV_N;
        float var = stats_sum(stats, 128 + col) * INV_N - mu * mu;
        float rs = rsqrtf(var + BN_EPS);
        c[j] = gamma[col] * rs;
        b[j] = beta[col] - mu * c[j];
    }
    int beg = gstart[g];
    int end = gstart[g + 1];
    float sa[8];
#pragma unroll
    for (int j = 0; j < 8; j++) sa[j] = 0.f;
    // slice = c0>>5 = ci>>2, off = c0&31 = (ci&3)*8
    const unsigned short* base = h_s + (size_t)(ci >> 2) * SLICE_STRIDE + (ci & 3) * 8;
    for (int i = beg + grp; i < end; i += 16) {
        bf16x8 v = *(const bf16x8*)(base + (size_t)i * 32);
#pragma unroll
        for (int j = 0; j < 8; j++)
            sa[j] += fmaxf(b2f((unsigned short)v[j]) * c[j] + b[j], 0.f);
    }
#pragma unroll
    for (int j = 0; j < 8; j++) red[grp][c0 + j] = sa[j];
    __syncthreads();
    if (t < 128) {
        float cnt = fmaxf((float)(end - beg), 1.0f);
        float tot = 0.f;
#pragma unroll
        for (int r = 0; r < 16; r++) tot += red[r][t];
        out[(size_t)g * 128 + t] = tot / cnt;
    }
}

// ---------------------------------------------------------------------------
extern "C" void kernel_launch(void* const* d_in, const int* in_sizes, int n_in,
                              void* d_out, int out_size, void* d_ws, size_t ws_size,
                              hipStream_t stream) {
    const float* x    = (const float*)d_in[0];
    const int*   ei   = (const int*)d_in[1];
    const int*   src  = ei;
    const int*   dst  = ei + N_EDGES;
    const int*   batch = (const int*)d_in[2];
    const float* gw1  = (const float*)d_in[3];
    const float* gb1  = (const float*)d_in[4];
    const float* gw2  = (const float*)d_in[5];
    const float* gb2  = (const float*)d_in[6];
    const float* swl  = (const float*)d_in[7];
    const float* sbl  = (const float*)d_in[8];
    const float* swr  = (const float*)d_in[9];
    const float* bng  = (const float*)d_in[10];
    const float* bnb  = (const float*)d_in[11];
    float* out = (float*)d_out;

    // workspace layout (float units; bf16 buffers 16B-aligned)
    float* ws = (float*)d_ws;
    unsigned short* x16_s  = (unsigned short*)(ws + 0);         // sliced [4][50000][32]
    unsigned short* agg_s  = (unsigned short*)(ws + 3200000);
    unsigned short* hact_s = (unsigned short*)(ws + 6400000);
    unsigned short* hpre_s = (unsigned short*)(ws + 9600000);
    unsigned short* wt     = (unsigned short*)(ws + 12800000);  // 6*16384 u16
    float*          inv_deg= ws + 12850000;                     // 50000
    int*            row_beg= (int*)(ws + 12900000);             // 50000
    int*            cursor = (int*)(ws + 12950000);             // 50000 | total | stats(3*8*256)
    int*            total  = cursor + 50000;
    float*          stats  = (float*)(cursor + 50001);          // 3 layers x 8 replicas x 256
    unsigned short* csr_src= (unsigned short*)(ws + 13100000);  // 600000 u16
    int*            gstart = (int*)(ws + 13700000);             // 513

    const int ggrid = 512;
    const int ntiles32 = (N_NODES + 31) / 32;                   // 1563
    const int ntiles16 = (N_NODES + 15) / 16;                   // 3125
    const int gather_grid = GATHER_GROUPS * NSLICES;            // 3128

    // ---- init: cursor + total + stats in one memset ----
    hipMemsetAsync(cursor, 0, (50001 + 3 * 8 * 256) * sizeof(int), stream);

    // ---- prep: x->bf16 sliced, weights->bf16^T, degree count ----
    prep_kernel<<<CONVX_BLOCKS + WCONV_BLOCKS + DEG_BLOCKS, 256, 0, stream>>>(
        x, gw1, gw2, swl, swr, dst, x16_s, wt, cursor);

    // ---- CSR ----
    alloc_kernel<<<ALLOC_BLOCKS + 3, 256, 0, stream>>>(cursor, row_beg, inv_deg, total, batch, gstart);
    csr_fill_kernel<<<(N_EDGES + 255) / 256, 256, 0, stream>>>(src, dst, cursor, csr_src, N_EDGES);

    // ---- GIN ----
    gather_slice_kernel<false><<<gather_grid, 256, 0, stream>>>(
        x16_s, row_beg, cursor, csr_src, nullptr, agg_s);
    gemm_gin_kernel<<<ggrid, 256, 0, stream>>>(
        x16_s, agg_s, wt + 0 * 16384, wt + 1 * 16384, gb1, gb2,
        stats + 0 * 2048, hpre_s, N_NODES, ntiles32);
    finish_kernel<<<3125, 256, 0, stream>>>(
        hpre_s, stats + 0 * 2048, bng + 0 * HID, bnb + 0 * HID, hact_s);

    // ---- SAGE 0 ----
    gather_slice_kernel<true><<<gather_grid, 256, 0, stream>>>(
        hact_s, row_beg, cursor, csr_src, inv_deg, agg_s);
    gemm_dual_kernel<<<ggrid, 256, 0, stream>>>(
        agg_s, hact_s, wt + 2 * 16384, wt + 3 * 16384, sbl + 0 * HID,
        stats + 1 * 2048, hpre_s, N_NODES, ntiles16);
    finish_kernel<<<3125, 256, 0, stream>>>(
        hpre_s, stats + 1 * 2048, bng + 1 * HID, bnb + 1 * HID, hact_s);

    // ---- SAGE 1 ----
    gather_slice_kernel<true><<<gather_grid, 256, 0, stream>>>(
        hact_s, row_beg, cursor, csr_src, inv_deg, agg_s);
    gemm_dual_kernel<<<ggrid, 256, 0, stream>>>(
        agg_s, hact_s, wt + 4 * 16384, wt + 5 * 16384, sbl + 1 * HID,
        stats + 2 * 2048, hpre_s, N_NODES, ntiles16);

    // ---- pool (BN2 affine folded) ----
    pool_mean_kernel<<<N_GRAPHS, 256, 0, stream>>>(
        hpre_s, gstart, stats + 2 * 2048, bng + 2 * HID, bnb + 2 * HID, out);
}